// Round 4
// baseline (859.864 us; speedup 1.0000x reference)
//
#include <hip/hip_runtime.h>
#include <hip/hip_bf16.h>

constexpr int kN = 10000;
constexpr int kE = 25000;
constexpr int kB = 128;
constexpr int kNF = 32;
constexpr int kEF = 8;
constexpr int kD = 64;
constexpr int kGrp = 392;          // 64-edge groups (25088 padded)

typedef __attribute__((ext_vector_type(8))) short short8;
typedef __attribute__((ext_vector_type(4))) float floatx4;
typedef __attribute__((ext_vector_type(16))) float floatx16;

__device__ __forceinline__ unsigned short f2bf(float f) {
  unsigned u = __float_as_uint(f);
  u = (u + 0x7fffu + ((u >> 16) & 1u)) >> 16;   // RNE
  return (unsigned short)u;
}
__device__ __forceinline__ float sigmf(float x) { return 1.f / (1.f + __expf(-x)); }
__device__ __forceinline__ float tanh_(float x) { return 1.f - 2.f / (__expf(2.f * x) + 1.f); }

__device__ __forceinline__ unsigned cvtpk(float lo, float hi) {
  unsigned r;
  asm("v_cvt_pk_bf16_f32 %0, %1, %2" : "=v"(r) : "v"(lo), "v"(hi));
  return r;
}

// ============ fused setup: dense0 | hidden(block-image layout) | prep_b | deg | bounds ====
constexpr int kBlkDense = 2500;                 // kN*64/256
constexpr int kBlkHid   = 12544;                // 392*2*64*64/256
constexpr int kBlkPrep  = 258;                  // 1032 slots * 64 lanes / 256
constexpr int kBlkDeg   = 98;
constexpr int kB0H = kBlkDense;                 // 2500
constexpr int kB0P = kB0H + kBlkHid;            // 15044
constexpr int kB0G = kB0P + kBlkPrep;           // 15302
constexpr int kB0B = kB0G + kBlkDeg;            // 15400
constexpr int kBlkSetup = kB0B + 1;             // 15401

__global__ __launch_bounds__(256) void k_setup(
    const float* __restrict__ x, const float* __restrict__ W0, const float* __restrict__ b0,
    const float* __restrict__ ea, const float* __restrict__ We1, const float* __restrict__ be1,
    const float* __restrict__ We2, const float* __restrict__ be2,
    const int* __restrict__ ei, const int* __restrict__ batch,
    float* __restrict__ outn, unsigned short* __restrict__ hid3,
    unsigned short* __restrict__ Bc2, float* __restrict__ deg, int* __restrict__ start) {
  const int blk = blockIdx.x, t = threadIdx.x;
  if (blk < kB0H) {                   // ---- dense0: out = relu(x@W0+b0), [N,64]
    int gid = blk * 256 + t;
    int n = gid >> 6, f = gid & 63;
    float acc = b0[f];
    const float* xr = x + n * kNF;
#pragma unroll
    for (int j = 0; j < kNF; ++j) acc += xr[j] * W0[j * kD + f];
    outn[gid] = fmaxf(acc, 0.f);
  } else if (blk < kB0P) {            // ---- hidden: hid3[grp][by][h 64][e 64]
    int gid = (blk - kB0H) * 256 + t;
    int e_loc = gid & 63, h_loc = (gid >> 6) & 63, by = (gid >> 12) & 1, grp = gid >> 13;
    int e = grp * 64 + e_loc, h = by * 64 + h_loc;
    float r = 0.f;
    if (e < kE) {
      float acc = be1[h];
      const float* er = ea + e * kEF;
#pragma unroll
      for (int j = 0; j < kEF; ++j) acc += er[j] * We1[j * 128 + h];
      r = fmaxf(acc, 0.f);
    }
    hid3[gid] = f2bf(r);
  } else if (blk < kB0G) {            // ---- prep B: fragment-major Bc2 (32x32x16)
    int lg = (blk - kB0P) * 256 + t;
    int lane = lg & 63, slot = lg >> 6;            // slot 0..1031
    int fcol, dbase;
    const float* srcmat;
    if (slot < 1024) {
      int nf_ = slot & 1, hdb = slot >> 1;         // slot = (h*4+db)*2+nf
      int db = hdb & 3, h = hdb >> 2;
      fcol = nf_ * 32 + (lane & 31);
      dbase = db * 16 + (lane >> 5) * 8;
      srcmat = We2 + (size_t)h * 4096;
    } else {
      int s = slot - 1024;
      int db = s >> 1, nf_ = s & 1;
      fcol = nf_ * 32 + (lane & 31);
      dbase = db * 16 + (lane >> 5) * 8;
      srcmat = be2;
    }
    unsigned short v[8];
#pragma unroll
    for (int j = 0; j < 8; ++j) v[j] = f2bf(srcmat[(size_t)(dbase + j) * 64 + fcol]);
    *(short8*)(Bc2 + (size_t)slot * 512 + lane * 8) = *(short8*)v;
  } else if (blk < kB0B) {            // ---- degree
    int e = (blk - kB0G) * 256 + t;
    if (e < kE) atomicAdd(&deg[ei[kE + e]], 1.f);
  } else {                            // ---- per-graph bounds (batch sorted)
    if (t > kB) return;
    int lo = 0, hi = kN;
    while (lo < hi) { int mid = (lo + hi) >> 1; if (batch[mid] < t) lo = mid + 1; else hi = mid; }
    start[t] = lo;
  }
}

// ============ message GEMM v3 ============
// Grid (392, 2): block = 64 edges x 64 f x K-half (64 h). 4 waves each take 16 h.
// Wave tile: M=64 (2 mf), N=64 (2 nf), K=16h x 64d. A-frag built once -> 4 MFMA.
// Partials reduced in LDS (ds_add_f32); one global atomic pass per block.
__global__ __launch_bounds__(256) void k_msg3(const int* __restrict__ ei,
    const float* __restrict__ outn, const unsigned short* __restrict__ hid3,
    const unsigned short* __restrict__ Bc2, float* __restrict__ agg) {
  __shared__ __align__(16) unsigned short hidS[64 * 64];   // [h_loc][e_loc], 8 KB
  __shared__ __align__(16) float res[64 * 64];             // [e][f], 16 KB
  const int t = threadIdx.x, lane = t & 63, wave = t >> 6;
  const int er = lane & 31, hi5 = lane >> 5;
  const int grp = blockIdx.x, by = blockIdx.y;
  // stage hid image (8 KB): linear [h][e] copy, 2 x 1KB per wave
  const char* hsrc = (const char*)(hid3 + ((size_t)grp * 2 + by) * 4096);
#pragma unroll
  for (int i = 0; i < 2; ++i) {
    int off = (wave * 2 + i) * 1024 + lane * 16;
    __builtin_amdgcn_global_load_lds(
        (const __attribute__((address_space(1))) void*)(hsrc + off),
        (__attribute__((address_space(3))) void*)((char*)hidS + off), 16, 0, 0);
  }
  // zero result buffer (64B/thread)
#pragma unroll
  for (int i = 0; i < 4; ++i) {
    float4 z = {0.f, 0.f, 0.f, 0.f};
    *(float4*)(res + t * 16 + i * 4) = z;
  }
  // gather out[src] rows: 2 mf x 4 db x 2 quads (64 VGPR)
  floatx4 o[2][4][2];
#pragma unroll
  for (int mf = 0; mf < 2; ++mf) {
    int e = grp * 64 + mf * 32 + er;
    int s = (e < kE) ? ei[e] : 0;
    const float* base = outn + (size_t)s * 64 + hi5 * 8;
#pragma unroll
    for (int db = 0; db < 4; ++db) {
      o[mf][db][0] = *(const floatx4*)(base + db * 16);
      o[mf][db][1] = *(const floatx4*)(base + db * 16 + 4);
    }
  }
  __syncthreads();   // hidS + res ready

  floatx16 acc[2][2];
#pragma unroll
  for (int mf = 0; mf < 2; ++mf)
#pragma unroll
    for (int nf = 0; nf < 2; ++nf)
#pragma unroll
      for (int i = 0; i < 16; ++i) acc[mf][nf][i] = 0.f;

  const int h0 = wave * 16;
#pragma unroll 2
  for (int hh = 0; hh < 16; ++hh) {
    int hl = h0 + hh;
    float hv[2];
#pragma unroll
    for (int mf = 0; mf < 2; ++mf) {
      unsigned short hs = hidS[hl * 64 + mf * 32 + er];
      hv[mf] = __uint_as_float(((unsigned)hs) << 16);
    }
    int hg = by * 64 + hl;
#pragma unroll
    for (int db = 0; db < 4; ++db) {
      short8 bv0 = *(const short8*)(Bc2 + ((size_t)((hg * 4 + db) * 2 + 0) * 512 + lane * 8));
      short8 bv1 = *(const short8*)(Bc2 + ((size_t)((hg * 4 + db) * 2 + 1) * 512 + lane * 8));
#pragma unroll
      for (int mf = 0; mf < 2; ++mf) {
        floatx4 va = o[mf][db][0] * hv[mf];
        floatx4 vb = o[mf][db][1] * hv[mf];
        union { uint4 u; short8 s; } U;
        U.u.x = cvtpk(va.x, va.y);
        U.u.y = cvtpk(va.z, va.w);
        U.u.z = cvtpk(vb.x, vb.y);
        U.u.w = cvtpk(vb.z, vb.w);
        acc[mf][0] = __builtin_amdgcn_mfma_f32_32x32x16_bf16(U.s, bv0, acc[mf][0], 0, 0, 0);
        acc[mf][1] = __builtin_amdgcn_mfma_f32_32x32x16_bf16(U.s, bv1, acc[mf][1], 0, 0, 0);
      }
    }
  }
  if (by == 1 && wave == 3) {   // bias chunk: msg += out @ reshape(be2,64,64)
#pragma unroll
    for (int db = 0; db < 4; ++db) {
      short8 bv0 = *(const short8*)(Bc2 + ((size_t)(1024 + db * 2 + 0) * 512 + lane * 8));
      short8 bv1 = *(const short8*)(Bc2 + ((size_t)(1024 + db * 2 + 1) * 512 + lane * 8));
#pragma unroll
      for (int mf = 0; mf < 2; ++mf) {
        floatx4 va = o[mf][db][0], vb = o[mf][db][1];
        union { uint4 u; short8 s; } U;
        U.u.x = cvtpk(va.x, va.y);
        U.u.y = cvtpk(va.z, va.w);
        U.u.z = cvtpk(vb.x, vb.y);
        U.u.w = cvtpk(vb.z, vb.w);
        acc[mf][0] = __builtin_amdgcn_mfma_f32_32x32x16_bf16(U.s, bv0, acc[mf][0], 0, 0, 0);
        acc[mf][1] = __builtin_amdgcn_mfma_f32_32x32x16_bf16(U.s, bv1, acc[mf][1], 0, 0, 0);
      }
    }
  }
  // reduce partials across the 4 waves in LDS
#pragma unroll
  for (int mf = 0; mf < 2; ++mf)
#pragma unroll
    for (int nf = 0; nf < 2; ++nf)
#pragma unroll
      for (int reg = 0; reg < 16; ++reg) {
        int row = (reg & 3) + 8 * (reg >> 2) + 4 * hi5 + mf * 32;
        atomicAdd(&res[row * 64 + nf * 32 + er], acc[mf][nf][reg]);
      }
  __syncthreads();
  // one global-atomic pass: thread t -> edge row t>>2, 16 f
  int e_loc = t >> 2, f0 = (t & 3) * 16;
  int e = grp * 64 + e_loc;
  if (e < kE) {
    int dst = ei[kE + e];
    float* ap = agg + (size_t)dst * 64 + f0;
#pragma unroll
    for (int j = 0; j < 16; ++j) atomicAdd(ap + j, res[e_loc * 64 + f0 + j]);
  }
}

// ============ fused NNConv-combine + GRU cell (16 nodes/block); self-zeros agg ============
__global__ __launch_bounds__(256) void k_update(const float* __restrict__ agg_in,
    const float* __restrict__ deg, const float* __restrict__ root,
    const float* __restrict__ convb, const float* __restrict__ Wi,
    const float* __restrict__ bi, const float* __restrict__ Wh,
    const float* __restrict__ bh, float* __restrict__ out, float* __restrict__ agg_clr) {
  __shared__ float sh_out[16][64];
  __shared__ float sh_m[16][64];
  int t = threadIdx.x, lane = t & 63, w = t >> 6;
  int nb = blockIdx.x * 16;
#pragma unroll
  for (int i = 0; i < 4; ++i) {
    int idx = t + i * 256;
    sh_out[idx >> 6][idx & 63] = out[(size_t)(nb + (idx >> 6)) * 64 + (idx & 63)];
  }
  __syncthreads();
  int n0 = w * 4;
  float acc[4];
#pragma unroll
  for (int i = 0; i < 4; ++i) {
    int n = nb + n0 + i;
    float dg = fmaxf(deg[n], 1.f);
    acc[i] = agg_in[(size_t)n * 64 + lane] / dg + convb[lane];
    agg_clr[(size_t)n * 64 + lane] = 0.f;        // ready for next iteration / next call
  }
  for (int d = 0; d < 64; ++d) {
    float rv = root[d * 64 + lane];
#pragma unroll
    for (int i = 0; i < 4; ++i) acc[i] += sh_out[n0 + i][d] * rv;
  }
#pragma unroll
  for (int i = 0; i < 4; ++i) sh_m[n0 + i][lane] = fmaxf(acc[i], 0.f);
  __syncthreads();
  float ir[4] = {}, iz[4] = {}, ig[4] = {}, hr[4] = {}, hz[4] = {}, hg[4] = {};
  for (int d = 0; d < 64; ++d) {
    float wi0 = Wi[d * 192 + lane], wi1 = Wi[d * 192 + 64 + lane], wi2 = Wi[d * 192 + 128 + lane];
    float wh0 = Wh[d * 192 + lane], wh1 = Wh[d * 192 + 64 + lane], wh2 = Wh[d * 192 + 128 + lane];
#pragma unroll
    for (int i = 0; i < 4; ++i) {
      float mv = sh_m[n0 + i][d], hv = sh_out[n0 + i][d];
      ir[i] += mv * wi0; iz[i] += mv * wi1; ig[i] += mv * wi2;
      hr[i] += hv * wh0; hz[i] += hv * wh1; hg[i] += hv * wh2;
    }
  }
  float bi0 = bi[lane], bi1 = bi[64 + lane], bi2 = bi[128 + lane];
  float bh0 = bh[lane], bh1 = bh[64 + lane], bh2 = bh[128 + lane];
#pragma unroll
  for (int i = 0; i < 4; ++i) {
    float r = sigmf(ir[i] + bi0 + hr[i] + bh0);
    float z = sigmf(iz[i] + bi1 + hz[i] + bh1);
    float nn = tanh_(ig[i] + bi2 + r * (hg[i] + bh2));
    float h = sh_out[n0 + i][lane];
    out[(size_t)(nb + n0 + i) * 64 + lane] = (1.f - z) * nn + z * h;
  }
}

// ============ all 3 Set2Set steps + head1 in one kernel (block = graph) ============
__global__ __launch_bounds__(256) void k_s2s3(const float* __restrict__ out,
    const int* __restrict__ start, const float* __restrict__ Wli,
    const float* __restrict__ bli, const float* __restrict__ Wlh,
    const float* __restrict__ blh, const float* __restrict__ Wr1,
    const float* __restrict__ br1, float* __restrict__ y1) {
  __shared__ float qs[128], hls[64], cls[64], gates[256];
  __shared__ float ebuf[1024];
  __shared__ float part[4][64];
  __shared__ float sred[8];
  int b = blockIdx.x, t = threadIdx.x, lane = t & 63, w = t >> 6;
  if (t < 128) qs[t] = 0.f;
  if (t < 64) { hls[t] = 0.f; cls[t] = 0.f; }
  int s0 = start[b], s1 = start[b + 1];
  int cnt = s1 - s0; if (cnt > 1024) cnt = 1024;
  __syncthreads();
  for (int it = 0; it < 3; ++it) {
    float g = bli[t] + blh[t];
    for (int j = 0; j < 128; ++j) g += qs[j] * Wli[j * 256 + t];
    for (int j = 0; j < 64; ++j) g += hls[j] * Wlh[j * 256 + t];
    gates[t] = g;
    __syncthreads();
    if (t < 64) {                      // gate order i, f, g, o
      float ig = sigmf(gates[t]), fg = sigmf(gates[64 + t]);
      float gg = tanh_(gates[128 + t]), og = sigmf(gates[192 + t]);
      float c = fg * cls[t] + ig * gg;
      float h = og * tanh_(c);
      cls[t] = c; hls[t] = h;
      qs[t] = h;                       // q part of q_star
    }
    __syncthreads();
    for (int idx = w; idx < cnt; idx += 4) {           // e[n] = <out[n], q>
      int node = s0 + idx;
      float p = out[(size_t)node * 64 + lane] * hls[lane];
#pragma unroll
      for (int m = 1; m < 64; m <<= 1) p += __shfl_xor(p, m, 64);
      if (lane == 0) ebuf[idx] = p;
    }
    __syncthreads();
    float mx = -3.4e38f;
    for (int idx = t; idx < cnt; idx += 256) mx = fmaxf(mx, ebuf[idx]);
#pragma unroll
    for (int m = 1; m < 64; m <<= 1) mx = fmaxf(mx, __shfl_xor(mx, m, 64));
    if (lane == 0) sred[w] = mx;
    __syncthreads();
    mx = fmaxf(fmaxf(sred[0], sred[1]), fmaxf(sred[2], sred[3]));
    float s = 0.f;
    for (int idx = t; idx < cnt; idx += 256) {
      float a = __expf(ebuf[idx] - mx);
      ebuf[idx] = a; s += a;
    }
#pragma unroll
    for (int m = 1; m < 64; m <<= 1) s += __shfl_xor(s, m, 64);
    if (lane == 0) sred[4 + w] = s;
    __syncthreads();
    s = sred[4] + sred[5] + sred[6] + sred[7];
    float rs = 1.f / fmaxf(s, 1e-12f);
    float pr = 0.f;
    for (int idx = w; idx < cnt; idx += 4) {
      int node = s0 + idx;
      pr += ebuf[idx] * out[(size_t)node * 64 + lane];
    }
    part[w][lane] = pr;
    __syncthreads();
    if (t < 64)
      qs[64 + t] = (part[0][t] + part[1][t] + part[2][t] + part[3][t]) * rs;
    __syncthreads();
  }
  if (t < 64) {                        // head1: y1 = q_star @ Wr1 + br1
    float acc = br1[t];
    for (int j = 0; j < 128; ++j) acc += qs[j] * Wr1[j * 64 + t];
    y1[b * 64 + t] = acc;
  }
}

// ============ head2: BatchNorm (batch stats) + relu + Wr2 ============
__global__ __launch_bounds__(256) void k_head2(const float* __restrict__ y1,
    const float* __restrict__ gamma, const float* __restrict__ beta,
    const float* __restrict__ Wr2, const float* __restrict__ br2,
    float* __restrict__ outp) {
  __shared__ float mu[64], ri[64];
  int t = threadIdx.x;
  if (t < 64) {
    float s1 = 0.f, s2 = 0.f;
    for (int b = 0; b < kB; ++b) { float v = y1[b * 64 + t]; s1 += v; s2 += v * v; }
    float m = s1 / (float)kB;
    mu[t] = m; ri[t] = rsqrtf(s2 / (float)kB - m * m + 1e-5f);
  }
  __syncthreads();
  if (t < kB) {
    float acc = br2[0];
    for (int f = 0; f < 64; ++f) {
      float v = (y1[t * 64 + f] - mu[f]) * ri[f] * gamma[f] + beta[f];
      acc += fmaxf(v, 0.f) * Wr2[f];
    }
    outp[t] = acc;
  }
}

extern "C" void kernel_launch(void* const* d_in, const int* in_sizes, int n_in,
                              void* d_out, int out_size, void* d_ws, size_t ws_size,
                              hipStream_t stream) {
  const float* x     = (const float*)d_in[0];
  const int*   ei    = (const int*)d_in[1];
  const float* ea    = (const float*)d_in[2];
  const int*   batch = (const int*)d_in[3];
  const float* W0    = (const float*)d_in[4];
  const float* b0    = (const float*)d_in[5];
  const float* We1   = (const float*)d_in[6];
  const float* be1   = (const float*)d_in[7];
  const float* We2   = (const float*)d_in[8];
  const float* be2   = (const float*)d_in[9];
  const float* root  = (const float*)d_in[10];
  const float* convb = (const float*)d_in[11];
  const float* Wi    = (const float*)d_in[12];
  const float* bi    = (const float*)d_in[13];
  const float* Wh    = (const float*)d_in[14];
  const float* bh    = (const float*)d_in[15];
  const float* Wli   = (const float*)d_in[16];
  const float* bli   = (const float*)d_in[17];
  const float* Wlh   = (const float*)d_in[18];
  const float* blh   = (const float*)d_in[19];
  const float* Wr1   = (const float*)d_in[20];
  const float* br1   = (const float*)d_in[21];
  const float* gamma = (const float*)d_in[22];
  const float* beta  = (const float*)d_in[23];
  const float* Wr2   = (const float*)d_in[24];
  const float* br2   = (const float*)d_in[25];
  (void)in_sizes; (void)n_in; (void)out_size; (void)ws_size;

  char* ws = (char*)d_ws;
  size_t off = 0;
  auto take = [&](size_t bytes) {
    char* p = ws + off;
    off += (bytes + 255) & ~(size_t)255;
    return p;
  };
  // zero-region (one memset covers deg..agg, contiguous)
  float* deg  = (float*)take((size_t)kN * 4);
  float* agg  = (float*)take((size_t)kN * kD * 4);
  size_t zeroBytes = off;
  int*   start = (int*)take(256 * 4);
  float* outn  = (float*)take((size_t)kN * kD * 4);
  unsigned short* hid3 = (unsigned short*)take((size_t)kGrp * 2 * 4096 * 2);  // 6.4 MB
  unsigned short* Bc2  = (unsigned short*)take((size_t)1032 * 512 * 2);       // 1.03 MB
  float* y1    = (float*)take((size_t)kB * 64 * 4);

  hipMemsetAsync(deg, 0, zeroBytes, stream);
  k_setup<<<kBlkSetup, 256, 0, stream>>>(x, W0, b0, ea, We1, be1, We2, be2, ei, batch,
                                         outn, hid3, Bc2, deg, start);
  dim3 gm(kGrp, 2);
  for (int s = 0; s < 3; ++s) {
    k_msg3<<<gm, 256, 0, stream>>>(ei, outn, hid3, Bc2, agg);
    k_update<<<kN / 16, 256, 0, stream>>>(agg, deg, root, convb, Wi, bi, Wh, bh, outn, agg);
  }
  k_s2s3<<<kB, 256, 0, stream>>>(outn, start, Wli, bli, Wlh, blh, Wr1, br1, y1);
  k_head2<<<1, 256, 0, stream>>>(y1, gamma, beta, Wr2, br2, (float*)d_out);
}

// Round 5
// 353.707 us; speedup vs baseline: 2.4310x; 2.4310x over previous
//
#include <hip/hip_runtime.h>
#include <hip/hip_bf16.h>

constexpr int kN = 10000;
constexpr int kE = 25000;
constexpr int kB = 128;
constexpr int kNF = 32;
constexpr int kEF = 8;
constexpr int kD = 64;
constexpr int kGrp = 392;          // 64-edge groups (25088 padded)

typedef __attribute__((ext_vector_type(8))) short short8;
typedef __attribute__((ext_vector_type(4))) float floatx4;
typedef __attribute__((ext_vector_type(16))) float floatx16;

__device__ __forceinline__ unsigned short f2bf(float f) {
  unsigned u = __float_as_uint(f);
  u = (u + 0x7fffu + ((u >> 16) & 1u)) >> 16;   // RNE
  return (unsigned short)u;
}
__device__ __forceinline__ float sigmf(float x) { return 1.f / (1.f + __expf(-x)); }
__device__ __forceinline__ float tanh_(float x) { return 1.f - 2.f / (__expf(2.f * x) + 1.f); }

__device__ __forceinline__ unsigned cvtpk(float lo, float hi) {
  unsigned r;
  asm("v_cvt_pk_bf16_f32 %0, %1, %2" : "=v"(r) : "v"(lo), "v"(hi));
  return r;
}

// ============ fused setup: dense0 | hidden(tile layout) | prep_b | deg | bounds ====
constexpr int kBlkDense = 2500;                 // kN*64/256
constexpr int kBlkHid   = 12544;                // 392*128*64/256
constexpr int kBlkPrep  = 258;                  // 1032 slots * 64 lanes / 256
constexpr int kBlkDeg   = 98;
constexpr int kB0H = kBlkDense;                 // 2500
constexpr int kB0P = kB0H + kBlkHid;            // 15044
constexpr int kB0G = kB0P + kBlkPrep;           // 15302
constexpr int kB0B = kB0G + kBlkDeg;            // 15400
constexpr int kBlkSetup = kB0B + 1;             // 15401

__global__ __launch_bounds__(256) void k_setup(
    const float* __restrict__ x, const float* __restrict__ W0, const float* __restrict__ b0,
    const float* __restrict__ ea, const float* __restrict__ We1, const float* __restrict__ be1,
    const float* __restrict__ We2, const float* __restrict__ be2,
    const int* __restrict__ ei, const int* __restrict__ batch,
    float* __restrict__ outn, unsigned short* __restrict__ hid5,
    unsigned short* __restrict__ Bc2, float* __restrict__ deg, int* __restrict__ start) {
  const int blk = blockIdx.x, t = threadIdx.x;
  if (blk < kB0H) {                   // ---- dense0: out = relu(x@W0+b0), [N,64]
    int gid = blk * 256 + t;
    int n = gid >> 6, f = gid & 63;
    float acc = b0[f];
    const float* xr = x + n * kNF;
#pragma unroll
    for (int j = 0; j < kNF; ++j) acc += xr[j] * W0[j * kD + f];
    outn[gid] = fmaxf(acc, 0.f);
  } else if (blk < kB0P) {            // ---- hidden: hid5[grp][h 128][e 64]
    int gid = (blk - kB0H) * 256 + t;
    int e_loc = gid & 63, h = (gid >> 6) & 127, grp = gid >> 13;
    int e = grp * 64 + e_loc;
    float r = 0.f;
    if (e < kE) {
      float acc = be1[h];
      const float* er = ea + e * kEF;
#pragma unroll
      for (int j = 0; j < kEF; ++j) acc += er[j] * We1[j * 128 + h];
      r = fmaxf(acc, 0.f);
    }
    hid5[gid] = f2bf(r);
  } else if (blk < kB0G) {            // ---- prep B: fragment-major Bc2 (32x32x16)
    int lg = (blk - kB0P) * 256 + t;
    int lane = lg & 63, slot = lg >> 6;            // slot 0..1031
    int fcol, dbase;
    const float* srcmat;
    if (slot < 1024) {
      int nf_ = slot & 1, hdb = slot >> 1;         // slot = (h*4+db)*2+nf
      int db = hdb & 3, h = hdb >> 2;
      fcol = nf_ * 32 + (lane & 31);
      dbase = db * 16 + (lane >> 5) * 8;
      srcmat = We2 + (size_t)h * 4096;
    } else {
      int s = slot - 1024;
      int db = s >> 1, nf_ = s & 1;
      fcol = nf_ * 32 + (lane & 31);
      dbase = db * 16 + (lane >> 5) * 8;
      srcmat = be2;
    }
    unsigned short v[8];
#pragma unroll
    for (int j = 0; j < 8; ++j) v[j] = f2bf(srcmat[(size_t)(dbase + j) * 64 + fcol]);
    *(short8*)(Bc2 + (size_t)slot * 512 + lane * 8) = *(short8*)v;
  } else if (blk < kB0B) {            // ---- degree
    int e = (blk - kB0G) * 256 + t;
    if (e < kE) atomicAdd(&deg[ei[kE + e]], 1.f);
  } else {                            // ---- per-graph bounds (batch sorted)
    if (t > kB) return;
    int lo = 0, hi = kN;
    while (lo < hi) { int mid = (lo + hi) >> 1; if (batch[mid] < t) lo = mid + 1; else hi = mid; }
    start[t] = lo;
  }
}

// ============ message GEMM v5 ============
// Grid (392, 2): block = 64 edges x f-half (by). 4 waves K-split (32 h each, full
// K inside block). Wave tile: M=64 (2 mf), N=32, A built once per bv -> 2 MFMA.
// Partials: per-wave private res region (plain ds_write), tree-reduced, then ONE
// global atomic pass per (e,f). B loads software-pipelined 4 deep.
__global__ __launch_bounds__(256) void k_msg5(const int* __restrict__ ei,
    const float* __restrict__ outn, const unsigned short* __restrict__ hid5,
    const unsigned short* __restrict__ Bc2, float* __restrict__ agg) {
  __shared__ __align__(16) unsigned short hidS[128 * 64];   // [h][e_loc], 16 KB
  __shared__ __align__(16) float res[4][2048];              // per-wave [e64][f32], 32 KB
  const int t = threadIdx.x, lane = t & 63, wave = t >> 6;
  const int er = lane & 31, hi5 = lane >> 5;
  const int grp = blockIdx.x, by = blockIdx.y;              // by = f-half
  {   // stage hid tile (16 KB, linear)
    const char* hsrc = (const char*)(hid5 + (size_t)grp * 8192);
#pragma unroll
    for (int i = 0; i < 4; ++i) {
      int off = (wave * 4 + i) * 1024 + lane * 16;
      __builtin_amdgcn_global_load_lds(
          (const __attribute__((address_space(1))) void*)(hsrc + off),
          (__attribute__((address_space(3))) void*)((char*)hidS + off), 16, 0, 0);
    }
  }
  // gather out[src] rows: 2 mf x 4 db x 2 quads (64 VGPR)
  floatx4 o[2][4][2];
#pragma unroll
  for (int mf = 0; mf < 2; ++mf) {
    int e = grp * 64 + mf * 32 + er;
    int s = (e < kE) ? ei[e] : 0;
    const float* base = outn + (size_t)s * 64 + hi5 * 8;
#pragma unroll
    for (int db = 0; db < 4; ++db) {
      o[mf][db][0] = *(const floatx4*)(base + db * 16);
      o[mf][db][1] = *(const floatx4*)(base + db * 16 + 4);
    }
  }
  __syncthreads();   // hidS ready

  floatx16 acc[2];
#pragma unroll
  for (int i = 0; i < 16; ++i) { acc[0][i] = 0.f; acc[1][i] = 0.f; }

  const int h0 = wave * 32;
  // slot(h,db) = (h*4+db)*2 + by -> linear in i = (h-h0)*4+db, stride 1024 elems
  const unsigned short* bp = Bc2 + ((size_t)(h0 * 8 + by) * 512) + lane * 8;
  short8 bvr[4];
#pragma unroll
  for (int j = 0; j < 4; ++j) bvr[j] = *(const short8*)(bp + (size_t)j * 1024);

  for (int ii = 0; ii < 128; ii += 4) {
    int h = h0 + (ii >> 2);
    unsigned hw0 = hidS[h * 64 + er];
    unsigned hw1 = hidS[h * 64 + 32 + er];
    float hv0 = __uint_as_float(hw0 << 16);
    float hv1 = __uint_as_float(hw1 << 16);
#pragma unroll
    for (int j = 0; j < 4; ++j) {
      short8 bv = bvr[j];
      bvr[j] = *(const short8*)(bp + (size_t)(ii + 4 + j) * 1024);  // prefetch (max slot 1031, in-bounds)
      union { uint4 u; short8 s; } U0, U1;
      floatx4 a0 = o[0][j][0] * hv0, b0 = o[0][j][1] * hv0;
      floatx4 a1 = o[1][j][0] * hv1, b1 = o[1][j][1] * hv1;
      U0.u.x = cvtpk(a0.x, a0.y); U0.u.y = cvtpk(a0.z, a0.w);
      U0.u.z = cvtpk(b0.x, b0.y); U0.u.w = cvtpk(b0.z, b0.w);
      U1.u.x = cvtpk(a1.x, a1.y); U1.u.y = cvtpk(a1.z, a1.w);
      U1.u.z = cvtpk(b1.x, b1.y); U1.u.w = cvtpk(b1.z, b1.w);
      acc[0] = __builtin_amdgcn_mfma_f32_32x32x16_bf16(U0.s, bv, acc[0], 0, 0, 0);
      acc[1] = __builtin_amdgcn_mfma_f32_32x32x16_bf16(U1.s, bv, acc[1], 0, 0, 0);
    }
  }
  if (wave == 3) {   // bias block: msg += out @ reshape(be2,64,64), this f-half
#pragma unroll
    for (int db = 0; db < 4; ++db) {
      short8 bv = *(const short8*)(Bc2 + ((size_t)(1024 + db * 2 + by) * 512) + lane * 8);
      union { uint4 u; short8 s; } U0, U1;
      floatx4 a0 = o[0][db][0], b0 = o[0][db][1];
      floatx4 a1 = o[1][db][0], b1 = o[1][db][1];
      U0.u.x = cvtpk(a0.x, a0.y); U0.u.y = cvtpk(a0.z, a0.w);
      U0.u.z = cvtpk(b0.x, b0.y); U0.u.w = cvtpk(b0.z, b0.w);
      U1.u.x = cvtpk(a1.x, a1.y); U1.u.y = cvtpk(a1.z, a1.w);
      U1.u.z = cvtpk(b1.x, b1.y); U1.u.w = cvtpk(b1.z, b1.w);
      acc[0] = __builtin_amdgcn_mfma_f32_32x32x16_bf16(U0.s, bv, acc[0], 0, 0, 0);
      acc[1] = __builtin_amdgcn_mfma_f32_32x32x16_bf16(U1.s, bv, acc[1], 0, 0, 0);
    }
  }
  // write K-partials to this wave's private region (no LDS atomics, 2-way-free banks)
#pragma unroll
  for (int mf = 0; mf < 2; ++mf)
#pragma unroll
    for (int reg = 0; reg < 16; ++reg) {
      int row = (reg & 3) + 8 * (reg >> 2) + 4 * hi5 + mf * 32;
      res[wave][row * 32 + er] = acc[mf][reg];
    }
  __syncthreads();
  // tree-reduce 4 partials; one global-atomic pass (8 floats / thread)
  int c = t * 8;
  float4 sA = *(const float4*)&res[0][c], sB = *(const float4*)&res[0][c + 4];
#pragma unroll
  for (int w = 1; w < 4; ++w) {
    float4 aA = *(const float4*)&res[w][c], aB = *(const float4*)&res[w][c + 4];
    sA.x += aA.x; sA.y += aA.y; sA.z += aA.z; sA.w += aA.w;
    sB.x += aB.x; sB.y += aB.y; sB.z += aB.z; sB.w += aB.w;
  }
  int e = grp * 64 + (t >> 2);
  if (e < kE) {
    int dst = ei[kE + e];
    float* ap = agg + (size_t)dst * 64 + by * 32 + (t & 3) * 8;
    atomicAdd(ap + 0, sA.x); atomicAdd(ap + 1, sA.y);
    atomicAdd(ap + 2, sA.z); atomicAdd(ap + 3, sA.w);
    atomicAdd(ap + 4, sB.x); atomicAdd(ap + 5, sB.y);
    atomicAdd(ap + 6, sB.z); atomicAdd(ap + 7, sB.w);
  }
}

// ============ fused NNConv-combine + GRU cell (16 nodes/block); self-zeros agg ============
__global__ __launch_bounds__(256) void k_update(const float* __restrict__ agg_in,
    const float* __restrict__ deg, const float* __restrict__ root,
    const float* __restrict__ convb, const float* __restrict__ Wi,
    const float* __restrict__ bi, const float* __restrict__ Wh,
    const float* __restrict__ bh, float* __restrict__ out, float* __restrict__ agg_clr) {
  __shared__ float sh_out[16][64];
  __shared__ float sh_m[16][64];
  int t = threadIdx.x, lane = t & 63, w = t >> 6;
  int nb = blockIdx.x * 16;
#pragma unroll
  for (int i = 0; i < 4; ++i) {
    int idx = t + i * 256;
    sh_out[idx >> 6][idx & 63] = out[(size_t)(nb + (idx >> 6)) * 64 + (idx & 63)];
  }
  __syncthreads();
  int n0 = w * 4;
  float acc[4];
#pragma unroll
  for (int i = 0; i < 4; ++i) {
    int n = nb + n0 + i;
    float dg = fmaxf(deg[n], 1.f);
    acc[i] = agg_in[(size_t)n * 64 + lane] / dg + convb[lane];
    agg_clr[(size_t)n * 64 + lane] = 0.f;        // ready for next iteration / next call
  }
  for (int d = 0; d < 64; ++d) {
    float rv = root[d * 64 + lane];
#pragma unroll
    for (int i = 0; i < 4; ++i) acc[i] += sh_out[n0 + i][d] * rv;
  }
#pragma unroll
  for (int i = 0; i < 4; ++i) sh_m[n0 + i][lane] = fmaxf(acc[i], 0.f);
  __syncthreads();
  float ir[4] = {}, iz[4] = {}, ig[4] = {}, hr[4] = {}, hz[4] = {}, hg[4] = {};
  for (int d = 0; d < 64; ++d) {
    float wi0 = Wi[d * 192 + lane], wi1 = Wi[d * 192 + 64 + lane], wi2 = Wi[d * 192 + 128 + lane];
    float wh0 = Wh[d * 192 + lane], wh1 = Wh[d * 192 + 64 + lane], wh2 = Wh[d * 192 + 128 + lane];
#pragma unroll
    for (int i = 0; i < 4; ++i) {
      float mv = sh_m[n0 + i][d], hv = sh_out[n0 + i][d];
      ir[i] += mv * wi0; iz[i] += mv * wi1; ig[i] += mv * wi2;
      hr[i] += hv * wh0; hz[i] += hv * wh1; hg[i] += hv * wh2;
    }
  }
  float bi0 = bi[lane], bi1 = bi[64 + lane], bi2 = bi[128 + lane];
  float bh0 = bh[lane], bh1 = bh[64 + lane], bh2 = bh[128 + lane];
#pragma unroll
  for (int i = 0; i < 4; ++i) {
    float r = sigmf(ir[i] + bi0 + hr[i] + bh0);
    float z = sigmf(iz[i] + bi1 + hz[i] + bh1);
    float nn = tanh_(ig[i] + bi2 + r * (hg[i] + bh2));
    float h = sh_out[n0 + i][lane];
    out[(size_t)(nb + n0 + i) * 64 + lane] = (1.f - z) * nn + z * h;
  }
}

// ============ all 3 Set2Set steps + head1 in one kernel (block = graph) ============
__global__ __launch_bounds__(256) void k_s2s3(const float* __restrict__ out,
    const int* __restrict__ start, const float* __restrict__ Wli,
    const float* __restrict__ bli, const float* __restrict__ Wlh,
    const float* __restrict__ blh, const float* __restrict__ Wr1,
    const float* __restrict__ br1, float* __restrict__ y1) {
  __shared__ float qs[128], hls[64], cls[64], gates[256];
  __shared__ float ebuf[1024];
  __shared__ float part[4][64];
  __shared__ float sred[8];
  int b = blockIdx.x, t = threadIdx.x, lane = t & 63, w = t >> 6;
  if (t < 128) qs[t] = 0.f;
  if (t < 64) { hls[t] = 0.f; cls[t] = 0.f; }
  int s0 = start[b], s1 = start[b + 1];
  int cnt = s1 - s0; if (cnt > 1024) cnt = 1024;
  __syncthreads();
  for (int it = 0; it < 3; ++it) {
    float g = bli[t] + blh[t];
    for (int j = 0; j < 128; ++j) g += qs[j] * Wli[j * 256 + t];
    for (int j = 0; j < 64; ++j) g += hls[j] * Wlh[j * 256 + t];
    gates[t] = g;
    __syncthreads();
    if (t < 64) {                      // gate order i, f, g, o
      float ig = sigmf(gates[t]), fg = sigmf(gates[64 + t]);
      float gg = tanh_(gates[128 + t]), og = sigmf(gates[192 + t]);
      float c = fg * cls[t] + ig * gg;
      float h = og * tanh_(c);
      cls[t] = c; hls[t] = h;
      qs[t] = h;                       // q part of q_star
    }
    __syncthreads();
    for (int idx = w; idx < cnt; idx += 4) {           // e[n] = <out[n], q>
      int node = s0 + idx;
      float p = out[(size_t)node * 64 + lane] * hls[lane];
#pragma unroll
      for (int m = 1; m < 64; m <<= 1) p += __shfl_xor(p, m, 64);
      if (lane == 0) ebuf[idx] = p;
    }
    __syncthreads();
    float mx = -3.4e38f;
    for (int idx = t; idx < cnt; idx += 256) mx = fmaxf(mx, ebuf[idx]);
#pragma unroll
    for (int m = 1; m < 64; m <<= 1) mx = fmaxf(mx, __shfl_xor(mx, m, 64));
    if (lane == 0) sred[w] = mx;
    __syncthreads();
    mx = fmaxf(fmaxf(sred[0], sred[1]), fmaxf(sred[2], sred[3]));
    float s = 0.f;
    for (int idx = t; idx < cnt; idx += 256) {
      float a = __expf(ebuf[idx] - mx);
      ebuf[idx] = a; s += a;
    }
#pragma unroll
    for (int m = 1; m < 64; m <<= 1) s += __shfl_xor(s, m, 64);
    if (lane == 0) sred[4 + w] = s;
    __syncthreads();
    s = sred[4] + sred[5] + sred[6] + sred[7];
    float rs = 1.f / fmaxf(s, 1e-12f);
    float pr = 0.f;
    for (int idx = w; idx < cnt; idx += 4) {
      int node = s0 + idx;
      pr += ebuf[idx] * out[(size_t)node * 64 + lane];
    }
    part[w][lane] = pr;
    __syncthreads();
    if (t < 64)
      qs[64 + t] = (part[0][t] + part[1][t] + part[2][t] + part[3][t]) * rs;
    __syncthreads();
  }
  if (t < 64) {                        // head1: y1 = q_star @ Wr1 + br1
    float acc = br1[t];
    for (int j = 0; j < 128; ++j) acc += qs[j] * Wr1[j * 64 + t];
    y1[b * 64 + t] = acc;
  }
}

// ============ head2: BatchNorm (batch stats) + relu + Wr2 ============
__global__ __launch_bounds__(256) void k_head2(const float* __restrict__ y1,
    const float* __restrict__ gamma, const float* __restrict__ beta,
    const float* __restrict__ Wr2, const float* __restrict__ br2,
    float* __restrict__ outp) {
  __shared__ float mu[64], ri[64];
  int t = threadIdx.x;
  if (t < 64) {
    float s1 = 0.f, s2 = 0.f;
    for (int b = 0; b < kB; ++b) { float v = y1[b * 64 + t]; s1 += v; s2 += v * v; }
    float m = s1 / (float)kB;
    mu[t] = m; ri[t] = rsqrtf(s2 / (float)kB - m * m + 1e-5f);
  }
  __syncthreads();
  if (t < kB) {
    float acc = br2[0];
    for (int f = 0; f < 64; ++f) {
      float v = (y1[t * 64 + f] - mu[f]) * ri[f] * gamma[f] + beta[f];
      acc += fmaxf(v, 0.f) * Wr2[f];
    }
    outp[t] = acc;
  }
}

extern "C" void kernel_launch(void* const* d_in, const int* in_sizes, int n_in,
                              void* d_out, int out_size, void* d_ws, size_t ws_size,
                              hipStream_t stream) {
  const float* x     = (const float*)d_in[0];
  const int*   ei    = (const int*)d_in[1];
  const float* ea    = (const float*)d_in[2];
  const int*   batch = (const int*)d_in[3];
  const float* W0    = (const float*)d_in[4];
  const float* b0    = (const float*)d_in[5];
  const float* We1   = (const float*)d_in[6];
  const float* be1   = (const float*)d_in[7];
  const float* We2   = (const float*)d_in[8];
  const float* be2   = (const float*)d_in[9];
  const float* root  = (const float*)d_in[10];
  const float* convb = (const float*)d_in[11];
  const float* Wi    = (const float*)d_in[12];
  const float* bi    = (const float*)d_in[13];
  const float* Wh    = (const float*)d_in[14];
  const float* bh    = (const float*)d_in[15];
  const float* Wli   = (const float*)d_in[16];
  const float* bli   = (const float*)d_in[17];
  const float* Wlh   = (const float*)d_in[18];
  const float* blh   = (const float*)d_in[19];
  const float* Wr1   = (const float*)d_in[20];
  const float* br1   = (const float*)d_in[21];
  const float* gamma = (const float*)d_in[22];
  const float* beta  = (const float*)d_in[23];
  const float* Wr2   = (const float*)d_in[24];
  const float* br2   = (const float*)d_in[25];
  (void)in_sizes; (void)n_in; (void)out_size; (void)ws_size;

  char* ws = (char*)d_ws;
  size_t off = 0;
  auto take = [&](size_t bytes) {
    char* p = ws + off;
    off += (bytes + 255) & ~(size_t)255;
    return p;
  };
  // zero-region (one memset covers deg..agg, contiguous)
  float* deg  = (float*)take((size_t)kN * 4);
  float* agg  = (float*)take((size_t)kN * kD * 4);
  size_t zeroBytes = off;
  int*   start = (int*)take(256 * 4);
  float* outn  = (float*)take((size_t)kN * kD * 4);
  unsigned short* hid5 = (unsigned short*)take((size_t)kGrp * 8192 * 2);      // 6.4 MB
  unsigned short* Bc2  = (unsigned short*)take((size_t)1032 * 512 * 2);       // 1.03 MB
  float* y1    = (float*)take((size_t)kB * 64 * 4);

  hipMemsetAsync(deg, 0, zeroBytes, stream);
  k_setup<<<kBlkSetup, 256, 0, stream>>>(x, W0, b0, ea, We1, be1, We2, be2, ei, batch,
                                         outn, hid5, Bc2, deg, start);
  dim3 gm(kGrp, 2);
  for (int s = 0; s < 3; ++s) {
    k_msg5<<<gm, 256, 0, stream>>>(ei, outn, hid5, Bc2, agg);
    k_update<<<kN / 16, 256, 0, stream>>>(agg, deg, root, convb, Wi, bi, Wh, bh, outn, agg);
  }
  k_s2s3<<<kB, 256, 0, stream>>>(outn, start, Wli, bli, Wlh, blh, Wr1, br1, y1);
  k_head2<<<1, 256, 0, stream>>>(y1, gamma, beta, Wr2, br2, (float*)d_out);
}

// Round 6
// 324.379 us; speedup vs baseline: 2.6508x; 1.0904x over previous
//
#include <hip/hip_runtime.h>
#include <hip/hip_bf16.h>

constexpr int kN = 10000;
constexpr int kE = 25000;
constexpr int kB = 128;
constexpr int kNF = 32;
constexpr int kEF = 8;
constexpr int kD = 64;
constexpr int kGrp = 784;          // 32-edge groups (25088 padded)

typedef __attribute__((ext_vector_type(8))) short short8;
typedef __attribute__((ext_vector_type(4))) float floatx4;
typedef __attribute__((ext_vector_type(16))) float floatx16;

__device__ __forceinline__ unsigned short f2bf(float f) {
  unsigned u = __float_as_uint(f);
  u = (u + 0x7fffu + ((u >> 16) & 1u)) >> 16;   // RNE
  return (unsigned short)u;
}
__device__ __forceinline__ float sigmf(float x) { return 1.f / (1.f + __expf(-x)); }
__device__ __forceinline__ float tanh_(float x) { return 1.f - 2.f / (__expf(2.f * x) + 1.f); }

__device__ __forceinline__ unsigned cvtpk(float lo, float hi) {
  unsigned r;
  asm("v_cvt_pk_bf16_f32 %0, %1, %2" : "=v"(r) : "v"(lo), "v"(hi));
  return r;
}

// ============ fused setup: dense0 | hidden([grp][h128][e32]) | prep_b | deg | bounds ====
constexpr int kBlkDense = 2500;                 // kN*64/256
constexpr int kBlkHid   = 12544;                // 784*4096/256
constexpr int kBlkPrep  = 258;                  // 1032 slots * 64 lanes / 256
constexpr int kBlkDeg   = 98;
constexpr int kB0H = kBlkDense;                 // 2500
constexpr int kB0P = kB0H + kBlkHid;            // 15044
constexpr int kB0G = kB0P + kBlkPrep;           // 15302
constexpr int kB0B = kB0G + kBlkDeg;            // 15400
constexpr int kBlkSetup = kB0B + 1;             // 15401

__global__ __launch_bounds__(256) void k_setup(
    const float* __restrict__ x, const float* __restrict__ W0, const float* __restrict__ b0,
    const float* __restrict__ ea, const float* __restrict__ We1, const float* __restrict__ be1,
    const float* __restrict__ We2, const float* __restrict__ be2,
    const int* __restrict__ ei, const int* __restrict__ batch,
    float* __restrict__ outn, unsigned short* __restrict__ hid6,
    unsigned short* __restrict__ Bc2, float* __restrict__ deg, int* __restrict__ start) {
  const int blk = blockIdx.x, t = threadIdx.x;
  if (blk < kB0H) {                   // ---- dense0: out = relu(x@W0+b0), [N,64]
    int gid = blk * 256 + t;
    int n = gid >> 6, f = gid & 63;
    float acc = b0[f];
    const float* xr = x + n * kNF;
#pragma unroll
    for (int j = 0; j < kNF; ++j) acc += xr[j] * W0[j * kD + f];
    outn[gid] = fmaxf(acc, 0.f);
  } else if (blk < kB0P) {            // ---- hidden: hid6[grp][h 128][e 32]
    int gid = (blk - kB0H) * 256 + t;
    int e_loc = gid & 31, h = (gid >> 5) & 127, grp = gid >> 12;
    int e = grp * 32 + e_loc;
    float r = 0.f;
    if (e < kE) {
      float acc = be1[h];
      const float* er = ea + e * kEF;
#pragma unroll
      for (int j = 0; j < kEF; ++j) acc += er[j] * We1[j * 128 + h];
      r = fmaxf(acc, 0.f);
    }
    hid6[gid] = f2bf(r);
  } else if (blk < kB0G) {            // ---- prep B: fragment-major Bc2 (32x32x16)
    int lg = (blk - kB0P) * 256 + t;
    int lane = lg & 63, slot = lg >> 6;            // slot 0..1031
    int fcol, dbase;
    const float* srcmat;
    if (slot < 1024) {
      int nf_ = slot & 1, hdb = slot >> 1;         // slot = (h*4+db)*2+nf
      int db = hdb & 3, h = hdb >> 2;
      fcol = nf_ * 32 + (lane & 31);
      dbase = db * 16 + (lane >> 5) * 8;
      srcmat = We2 + (size_t)h * 4096;
    } else {
      int s = slot - 1024;
      int db = s >> 1, nf_ = s & 1;
      fcol = nf_ * 32 + (lane & 31);
      dbase = db * 16 + (lane >> 5) * 8;
      srcmat = be2;
    }
    unsigned short v[8];
#pragma unroll
    for (int j = 0; j < 8; ++j) v[j] = f2bf(srcmat[(size_t)(dbase + j) * 64 + fcol]);
    *(short8*)(Bc2 + (size_t)slot * 512 + lane * 8) = *(short8*)v;
  } else if (blk < kB0B) {            // ---- degree
    int e = (blk - kB0G) * 256 + t;
    if (e < kE) atomicAdd(&deg[ei[kE + e]], 1.f);
  } else {                            // ---- per-graph bounds (batch sorted)
    if (t > kB) return;
    int lo = 0, hi = kN;
    while (lo < hi) { int mid = (lo + hi) >> 1; if (batch[mid] < t) lo = mid + 1; else hi = mid; }
    start[t] = lo;
  }
}

// ============ CSR build: scan (1 block) + scatter ============
__global__ __launch_bounds__(256) void k_csr(const float* __restrict__ deg,
                                             int* __restrict__ ptr) {
  __shared__ int ps[256];
  int t = threadIdx.x;
  int base = t * 40;                       // 256*40 = 10240 >= kN
  int s = 0;
#pragma unroll 8
  for (int j = 0; j < 40; ++j) {
    int n = base + j;
    if (n < kN) s += (int)deg[n];
  }
  ps[t] = s;
  __syncthreads();
  for (int off = 1; off < 256; off <<= 1) {
    int v = (t >= off) ? ps[t - off] : 0;
    __syncthreads();
    ps[t] += v;
    __syncthreads();
  }
  int run = ps[t] - s;                     // exclusive prefix of this chunk
  for (int j = 0; j < 40; ++j) {
    int n = base + j;
    if (n < kN) { ptr[n] = run; run += (int)deg[n]; }
  }
  if (t == 255) ptr[kN] = ps[255];
}

__global__ __launch_bounds__(256) void k_scatter(const int* __restrict__ ei,
    const int* __restrict__ ptr, int* __restrict__ cnt, int* __restrict__ csr) {
  int e = blockIdx.x * 256 + threadIdx.x;
  if (e < kE) {
    int d = ei[kE + e];
    int pos = atomicAdd(&cnt[d], 1);
    csr[ptr[d] + pos] = e;
  }
}

// ============ message GEMM v6 ============
// Grid 784: block = 32 edges x 64 f. 4 waves K-split (32 h each). Wave: M=32, N=64
// (2 nf) -> A built ONCE feeds 2 MFMAs. B prefetched 8-deep (one h ahead).
// K-partials to private LDS region, block-reduced, PLAIN stores to msg[e] (no atomics).
__global__ __launch_bounds__(256) void k_msg6(const int* __restrict__ ei,
    const float* __restrict__ outn, const unsigned short* __restrict__ hid6,
    const unsigned short* __restrict__ Bc2, float* __restrict__ msg) {
  __shared__ __align__(16) unsigned short hidS[128 * 32];   // [h][e_loc], 8 KB
  __shared__ __align__(16) float res[4][32 * 64];           // per-wave [e32][f64], 32 KB
  const int t = threadIdx.x, lane = t & 63, wave = t >> 6;
  const int er = lane & 31, hi5 = lane >> 5;
  const int grp = blockIdx.x, e0 = grp * 32;
  {   // stage hid tile (8 KB linear), 2 instrs/wave
    const char* hsrc = (const char*)(hid6 + (size_t)grp * 4096);
#pragma unroll
    for (int i = 0; i < 2; ++i) {
      int off = (wave * 2 + i) * 1024 + lane * 16;
      __builtin_amdgcn_global_load_lds(
          (const __attribute__((address_space(1))) void*)(hsrc + off),
          (__attribute__((address_space(3))) void*)((char*)hidS + off), 16, 0, 0);
    }
  }
  // B prefetch: 8 slots (one full h iteration) in flight
  const int h0 = wave * 32;
  const unsigned short* bp = Bc2 + (size_t)(h0 * 8) * 512 + lane * 8;
  short8 bvr[8];
#pragma unroll
  for (int j = 0; j < 8; ++j) bvr[j] = *(const short8*)(bp + (size_t)j * 512);
  // gather out[src] row: 4 db x 2 quads (32 VGPR); M=32 -> one edge per lane-pair
  floatx4 o[4][2];
  {
    int e = e0 + er;
    int s = (e < kE) ? ei[e] : 0;
    const float* base = outn + (size_t)s * 64 + hi5 * 8;
#pragma unroll
    for (int db = 0; db < 4; ++db) {
      o[db][0] = *(const floatx4*)(base + db * 16);
      o[db][1] = *(const floatx4*)(base + db * 16 + 4);
    }
  }
  __syncthreads();   // hidS ready

  floatx16 acc[2];
#pragma unroll
  for (int i = 0; i < 16; ++i) { acc[0][i] = 0.f; acc[1][i] = 0.f; }

  float hvc = __uint_as_float(((unsigned)hidS[h0 * 32 + er]) << 16);
  for (int hh = 0; hh < 32; ++hh) {
    // prefetch next h's hid scalar (wraps at end; value unused after last iter)
    unsigned short hsn = hidS[(h0 + ((hh + 1) & 31)) * 32 + er];
    const unsigned short* bpn = bp + (size_t)((hh + 1) * 8) * 512;
#pragma unroll
    for (int db = 0; db < 4; ++db) {
      short8 bv0 = bvr[db * 2], bv1 = bvr[db * 2 + 1];
      bvr[db * 2]     = *(const short8*)(bpn + (size_t)(db * 2) * 512);      // max slot 1031: in-bounds
      bvr[db * 2 + 1] = *(const short8*)(bpn + (size_t)(db * 2 + 1) * 512);
      floatx4 va = o[db][0] * hvc, vb = o[db][1] * hvc;
      union { uint4 u; short8 s; } U;
      U.u.x = cvtpk(va.x, va.y); U.u.y = cvtpk(va.z, va.w);
      U.u.z = cvtpk(vb.x, vb.y); U.u.w = cvtpk(vb.z, vb.w);
      acc[0] = __builtin_amdgcn_mfma_f32_32x32x16_bf16(U.s, bv0, acc[0], 0, 0, 0);
      acc[1] = __builtin_amdgcn_mfma_f32_32x32x16_bf16(U.s, bv1, acc[1], 0, 0, 0);
    }
    hvc = __uint_as_float(((unsigned)hsn) << 16);
  }
  if (wave == 3) {   // bias: msg += out @ reshape(be2,64,64)
#pragma unroll
    for (int db = 0; db < 4; ++db) {
      short8 bv0 = *(const short8*)(Bc2 + (size_t)(1024 + db * 2) * 512 + lane * 8);
      short8 bv1 = *(const short8*)(Bc2 + (size_t)(1024 + db * 2 + 1) * 512 + lane * 8);
      floatx4 va = o[db][0], vb = o[db][1];
      union { uint4 u; short8 s; } U;
      U.u.x = cvtpk(va.x, va.y); U.u.y = cvtpk(va.z, va.w);
      U.u.z = cvtpk(vb.x, vb.y); U.u.w = cvtpk(vb.z, vb.w);
      acc[0] = __builtin_amdgcn_mfma_f32_32x32x16_bf16(U.s, bv0, acc[0], 0, 0, 0);
      acc[1] = __builtin_amdgcn_mfma_f32_32x32x16_bf16(U.s, bv1, acc[1], 0, 0, 0);
    }
  }
  // K-partials to this wave's private region (plain ds_write)
#pragma unroll
  for (int nf = 0; nf < 2; ++nf)
#pragma unroll
    for (int reg = 0; reg < 16; ++reg) {
      int row = (reg & 3) + 8 * (reg >> 2) + 4 * hi5;
      res[wave][row * 64 + nf * 32 + er] = acc[nf][reg];
    }
  __syncthreads();
  // block reduce (4 partials) + plain coalesced store: t -> row t>>3, f-oct (t&7)*8
  int r = t >> 3, fo = (t & 7) * 8;
  float4 sA = *(const float4*)&res[0][r * 64 + fo];
  float4 sB = *(const float4*)&res[0][r * 64 + fo + 4];
#pragma unroll
  for (int w = 1; w < 4; ++w) {
    float4 aA = *(const float4*)&res[w][r * 64 + fo];
    float4 aB = *(const float4*)&res[w][r * 64 + fo + 4];
    sA.x += aA.x; sA.y += aA.y; sA.z += aA.z; sA.w += aA.w;
    sB.x += aB.x; sB.y += aB.y; sB.z += aB.z; sB.w += aB.w;
  }
  int e = e0 + r;
  if (e < kE) {
    *(float4*)(msg + (size_t)e * 64 + fo) = sA;
    *(float4*)(msg + (size_t)e * 64 + fo + 4) = sB;
  }
}

// ============ NNConv-combine + GRU cell; CSR message gather (16 nodes/block) ============
__global__ __launch_bounds__(256) void k_update(const float* __restrict__ msg,
    const int* __restrict__ ptr, const int* __restrict__ csr,
    const float* __restrict__ deg, const float* __restrict__ root,
    const float* __restrict__ convb, const float* __restrict__ Wi,
    const float* __restrict__ bi, const float* __restrict__ Wh,
    const float* __restrict__ bh, float* __restrict__ out) {
  __shared__ float sh_out[16][64];
  __shared__ float sh_m[16][64];
  int t = threadIdx.x, lane = t & 63, w = t >> 6;
  int nb = blockIdx.x * 16;
#pragma unroll
  for (int i = 0; i < 4; ++i) {
    int idx = t + i * 256;
    sh_out[idx >> 6][idx & 63] = out[(size_t)(nb + (idx >> 6)) * 64 + (idx & 63)];
  }
  __syncthreads();
  int n0 = w * 4;
  float acc[4];
#pragma unroll
  for (int i = 0; i < 4; ++i) {
    int n = nb + n0 + i;
    float dg = fmaxf(deg[n], 1.f);
    float s = 0.f;
    int p0 = ptr[n], p1 = ptr[n + 1];
    for (int k = p0; k < p1; ++k) s += msg[(size_t)csr[k] * 64 + lane];
    acc[i] = s / dg + convb[lane];
  }
  for (int d = 0; d < 64; ++d) {
    float rv = root[d * 64 + lane];
#pragma unroll
    for (int i = 0; i < 4; ++i) acc[i] += sh_out[n0 + i][d] * rv;
  }
#pragma unroll
  for (int i = 0; i < 4; ++i) sh_m[n0 + i][lane] = fmaxf(acc[i], 0.f);
  __syncthreads();
  float ir[4] = {}, iz[4] = {}, ig[4] = {}, hr[4] = {}, hz[4] = {}, hg[4] = {};
  for (int d = 0; d < 64; ++d) {
    float wi0 = Wi[d * 192 + lane], wi1 = Wi[d * 192 + 64 + lane], wi2 = Wi[d * 192 + 128 + lane];
    float wh0 = Wh[d * 192 + lane], wh1 = Wh[d * 192 + 64 + lane], wh2 = Wh[d * 192 + 128 + lane];
#pragma unroll
    for (int i = 0; i < 4; ++i) {
      float mv = sh_m[n0 + i][d], hv = sh_out[n0 + i][d];
      ir[i] += mv * wi0; iz[i] += mv * wi1; ig[i] += mv * wi2;
      hr[i] += hv * wh0; hz[i] += hv * wh1; hg[i] += hv * wh2;
    }
  }
  float bi0 = bi[lane], bi1 = bi[64 + lane], bi2 = bi[128 + lane];
  float bh0 = bh[lane], bh1 = bh[64 + lane], bh2 = bh[128 + lane];
#pragma unroll
  for (int i = 0; i < 4; ++i) {
    float r = sigmf(ir[i] + bi0 + hr[i] + bh0);
    float z = sigmf(iz[i] + bi1 + hz[i] + bh1);
    float nn = tanh_(ig[i] + bi2 + r * (hg[i] + bh2));
    float h = sh_out[n0 + i][lane];
    out[(size_t)(nb + n0 + i) * 64 + lane] = (1.f - z) * nn + z * h;
  }
}

// ============ all 3 Set2Set steps + head1 in one kernel (block = graph) ============
__global__ __launch_bounds__(256) void k_s2s3(const float* __restrict__ out,
    const int* __restrict__ start, const float* __restrict__ Wli,
    const float* __restrict__ bli, const float* __restrict__ Wlh,
    const float* __restrict__ blh, const float* __restrict__ Wr1,
    const float* __restrict__ br1, float* __restrict__ y1) {
  __shared__ float qs[128], hls[64], cls[64], gates[256];
  __shared__ float ebuf[1024];
  __shared__ float part[4][64];
  __shared__ float sred[8];
  int b = blockIdx.x, t = threadIdx.x, lane = t & 63, w = t >> 6;
  if (t < 128) qs[t] = 0.f;
  if (t < 64) { hls[t] = 0.f; cls[t] = 0.f; }
  int s0 = start[b], s1 = start[b + 1];
  int cnt = s1 - s0; if (cnt > 1024) cnt = 1024;
  __syncthreads();
  for (int it = 0; it < 3; ++it) {
    float g = bli[t] + blh[t];
    for (int j = 0; j < 128; ++j) g += qs[j] * Wli[j * 256 + t];
    for (int j = 0; j < 64; ++j) g += hls[j] * Wlh[j * 256 + t];
    gates[t] = g;
    __syncthreads();
    if (t < 64) {                      // gate order i, f, g, o
      float ig = sigmf(gates[t]), fg = sigmf(gates[64 + t]);
      float gg = tanh_(gates[128 + t]), og = sigmf(gates[192 + t]);
      float c = fg * cls[t] + ig * gg;
      float h = og * tanh_(c);
      cls[t] = c; hls[t] = h;
      qs[t] = h;                       // q part of q_star
    }
    __syncthreads();
    for (int idx = w; idx < cnt; idx += 4) {           // e[n] = <out[n], q>
      int node = s0 + idx;
      float p = out[(size_t)node * 64 + lane] * hls[lane];
#pragma unroll
      for (int m = 1; m < 64; m <<= 1) p += __shfl_xor(p, m, 64);
      if (lane == 0) ebuf[idx] = p;
    }
    __syncthreads();
    float mx = -3.4e38f;
    for (int idx = t; idx < cnt; idx += 256) mx = fmaxf(mx, ebuf[idx]);
#pragma unroll
    for (int m = 1; m < 64; m <<= 1) mx = fmaxf(mx, __shfl_xor(mx, m, 64));
    if (lane == 0) sred[w] = mx;
    __syncthreads();
    mx = fmaxf(fmaxf(sred[0], sred[1]), fmaxf(sred[2], sred[3]));
    float s = 0.f;
    for (int idx = t; idx < cnt; idx += 256) {
      float a = __expf(ebuf[idx] - mx);
      ebuf[idx] = a; s += a;
    }
#pragma unroll
    for (int m = 1; m < 64; m <<= 1) s += __shfl_xor(s, m, 64);
    if (lane == 0) sred[4 + w] = s;
    __syncthreads();
    s = sred[4] + sred[5] + sred[6] + sred[7];
    float rs = 1.f / fmaxf(s, 1e-12f);
    float pr = 0.f;
    for (int idx = w; idx < cnt; idx += 4) {
      int node = s0 + idx;
      pr += ebuf[idx] * out[(size_t)node * 64 + lane];
    }
    part[w][lane] = pr;
    __syncthreads();
    if (t < 64)
      qs[64 + t] = (part[0][t] + part[1][t] + part[2][t] + part[3][t]) * rs;
    __syncthreads();
  }
  if (t < 64) {                        // head1: y1 = q_star @ Wr1 + br1
    float acc = br1[t];
    for (int j = 0; j < 128; ++j) acc += qs[j] * Wr1[j * 64 + t];
    y1[b * 64 + t] = acc;
  }
}

// ============ head2: BatchNorm (batch stats) + relu + Wr2 ============
__global__ __launch_bounds__(256) void k_head2(const float* __restrict__ y1,
    const float* __restrict__ gamma, const float* __restrict__ beta,
    const float* __restrict__ Wr2, const float* __restrict__ br2,
    float* __restrict__ outp) {
  __shared__ float mu[64], ri[64];
  int t = threadIdx.x;
  if (t < 64) {
    float s1 = 0.f, s2 = 0.f;
    for (int b = 0; b < kB; ++b) { float v = y1[b * 64 + t]; s1 += v; s2 += v * v; }
    float m = s1 / (float)kB;
    mu[t] = m; ri[t] = rsqrtf(s2 / (float)kB - m * m + 1e-5f);
  }
  __syncthreads();
  if (t < kB) {
    float acc = br2[0];
    for (int f = 0; f < 64; ++f) {
      float v = (y1[t * 64 + f] - mu[f]) * ri[f] * gamma[f] + beta[f];
      acc += fmaxf(v, 0.f) * Wr2[f];
    }
    outp[t] = acc;
  }
}

extern "C" void kernel_launch(void* const* d_in, const int* in_sizes, int n_in,
                              void* d_out, int out_size, void* d_ws, size_t ws_size,
                              hipStream_t stream) {
  const float* x     = (const float*)d_in[0];
  const int*   ei    = (const int*)d_in[1];
  const float* ea    = (const float*)d_in[2];
  const int*   batch = (const int*)d_in[3];
  const float* W0    = (const float*)d_in[4];
  const float* b0    = (const float*)d_in[5];
  const float* We1   = (const float*)d_in[6];
  const float* be1   = (const float*)d_in[7];
  const float* We2   = (const float*)d_in[8];
  const float* be2   = (const float*)d_in[9];
  const float* root  = (const float*)d_in[10];
  const float* convb = (const float*)d_in[11];
  const float* Wi    = (const float*)d_in[12];
  const float* bi    = (const float*)d_in[13];
  const float* Wh    = (const float*)d_in[14];
  const float* bh    = (const float*)d_in[15];
  const float* Wli   = (const float*)d_in[16];
  const float* bli   = (const float*)d_in[17];
  const float* Wlh   = (const float*)d_in[18];
  const float* blh   = (const float*)d_in[19];
  const float* Wr1   = (const float*)d_in[20];
  const float* br1   = (const float*)d_in[21];
  const float* gamma = (const float*)d_in[22];
  const float* beta  = (const float*)d_in[23];
  const float* Wr2   = (const float*)d_in[24];
  const float* br2   = (const float*)d_in[25];
  (void)in_sizes; (void)n_in; (void)out_size; (void)ws_size;

  char* ws = (char*)d_ws;
  size_t off = 0;
  auto take = [&](size_t bytes) {
    char* p = ws + off;
    off += (bytes + 255) & ~(size_t)255;
    return p;
  };
  // zero-region: deg + cnt (contiguous, one memset)
  float* deg  = (float*)take((size_t)kN * 4);
  int*   cnt  = (int*)take((size_t)kN * 4);
  size_t zeroBytes = off;
  int*   ptr   = (int*)take((size_t)(kN + 1) * 4);
  int*   csr   = (int*)take((size_t)kE * 4);
  int*   start = (int*)take(256 * 4);
  float* outn  = (float*)take((size_t)kN * kD * 4);
  float* msg   = (float*)take((size_t)kGrp * 32 * kD * 4);                 // 6.4 MB
  unsigned short* hid6 = (unsigned short*)take((size_t)kGrp * 4096 * 2);   // 6.4 MB
  unsigned short* Bc2  = (unsigned short*)take((size_t)1032 * 512 * 2);    // 1.03 MB
  float* y1    = (float*)take((size_t)kB * 64 * 4);

  hipMemsetAsync(deg, 0, zeroBytes, stream);
  k_setup<<<kBlkSetup, 256, 0, stream>>>(x, W0, b0, ea, We1, be1, We2, be2, ei, batch,
                                         outn, hid6, Bc2, deg, start);
  k_csr<<<1, 256, 0, stream>>>(deg, ptr);
  k_scatter<<<(kE + 255) / 256, 256, 0, stream>>>(ei, ptr, cnt, csr);
  for (int s = 0; s < 3; ++s) {
    k_msg6<<<kGrp, 256, 0, stream>>>(ei, outn, hid6, Bc2, msg);
    k_update<<<kN / 16, 256, 0, stream>>>(msg, ptr, csr, deg, root, convb,
                                          Wi, bi, Wh, bh, outn);
  }
  k_s2s3<<<kB, 256, 0, stream>>>(outn, start, Wli, bli, Wlh, blh, Wr1, br1, y1);
  k_head2<<<1, 256, 0, stream>>>(y1, gamma, beta, Wr2, br2, (float*)d_out);
}

// Round 7
// 305.856 us; speedup vs baseline: 2.8113x; 1.0606x over previous
//
#include <hip/hip_runtime.h>
#include <hip/hip_bf16.h>

constexpr int kN = 10000;
constexpr int kE = 25000;
constexpr int kB = 128;
constexpr int kNF = 32;
constexpr int kEF = 8;
constexpr int kD = 64;
constexpr int kGrp = 392;          // 64-edge groups (25088 padded)
constexpr int kEPad = kGrp * 64;   // 25088

typedef __attribute__((ext_vector_type(8))) short short8;
typedef __attribute__((ext_vector_type(4))) float floatx4;
typedef __attribute__((ext_vector_type(16))) float floatx16;

__device__ __forceinline__ unsigned short f2bf(float f) {
  unsigned u = __float_as_uint(f);
  u = (u + 0x7fffu + ((u >> 16) & 1u)) >> 16;   // RNE
  return (unsigned short)u;
}
__device__ __forceinline__ float sigmf(float x) { return 1.f / (1.f + __expf(-x)); }
__device__ __forceinline__ float tanh_(float x) { return 1.f - 2.f / (__expf(2.f * x) + 1.f); }

__device__ __forceinline__ unsigned cvtpk(float lo, float hi) {
  unsigned r;
  asm("v_cvt_pk_bf16_f32 %0, %1, %2" : "=v"(r) : "v"(lo), "v"(hi));
  return r;
}

// ============ fused setup: dense0 | hidden([grp][h128][e64]) | prep_b | deg | bounds ====
constexpr int kBlkDense = 2500;                 // kN*64/256
constexpr int kBlkHid   = 12544;                // 392*128*64/256
constexpr int kBlkPrep  = 258;                  // 1032 slots * 64 lanes / 256
constexpr int kBlkDeg   = 98;
constexpr int kB0H = kBlkDense;                 // 2500
constexpr int kB0P = kB0H + kBlkHid;            // 15044
constexpr int kB0G = kB0P + kBlkPrep;           // 15302
constexpr int kB0B = kB0G + kBlkDeg;            // 15400
constexpr int kBlkSetup = kB0B + 1;             // 15401

__global__ __launch_bounds__(256) void k_setup(
    const float* __restrict__ x, const float* __restrict__ W0, const float* __restrict__ b0,
    const float* __restrict__ ea, const float* __restrict__ We1, const float* __restrict__ be1,
    const float* __restrict__ We2, const float* __restrict__ be2,
    const int* __restrict__ ei, const int* __restrict__ batch,
    float* __restrict__ outn, unsigned short* __restrict__ hid7,
    unsigned short* __restrict__ Bc2, float* __restrict__ deg, int* __restrict__ start) {
  const int blk = blockIdx.x, t = threadIdx.x;
  if (blk < kB0H) {                   // ---- dense0: out = relu(x@W0+b0), [N,64]
    int gid = blk * 256 + t;
    int n = gid >> 6, f = gid & 63;
    float acc = b0[f];
    const float* xr = x + n * kNF;
#pragma unroll
    for (int j = 0; j < kNF; ++j) acc += xr[j] * W0[j * kD + f];
    outn[gid] = fmaxf(acc, 0.f);
  } else if (blk < kB0P) {            // ---- hidden: hid7[grp][h 128][e 64]
    int gid = (blk - kB0H) * 256 + t;
    int e_loc = gid & 63, h = (gid >> 6) & 127, grp = gid >> 13;
    int e = grp * 64 + e_loc;
    float r = 0.f;
    if (e < kE) {
      float acc = be1[h];
      const float* er = ea + e * kEF;
#pragma unroll
      for (int j = 0; j < kEF; ++j) acc += er[j] * We1[j * 128 + h];
      r = fmaxf(acc, 0.f);
    }
    hid7[gid] = f2bf(r);
  } else if (blk < kB0G) {            // ---- prep B: fragment-major Bc2 (32x32x16)
    int lg = (blk - kB0P) * 256 + t;
    int lane = lg & 63, slot = lg >> 6;            // slot 0..1031
    int fcol, dbase;
    const float* srcmat;
    if (slot < 1024) {
      int nf_ = slot & 1, hdb = slot >> 1;         // slot = (h*4+db)*2+nf
      int db = hdb & 3, h = hdb >> 2;
      fcol = nf_ * 32 + (lane & 31);
      dbase = db * 16 + (lane >> 5) * 8;
      srcmat = We2 + (size_t)h * 4096;
    } else {
      int s = slot - 1024;
      int db = s >> 1, nf_ = s & 1;
      fcol = nf_ * 32 + (lane & 31);
      dbase = db * 16 + (lane >> 5) * 8;
      srcmat = be2;
    }
    unsigned short v[8];
#pragma unroll
    for (int j = 0; j < 8; ++j) v[j] = f2bf(srcmat[(size_t)(dbase + j) * 64 + fcol]);
    *(short8*)(Bc2 + (size_t)slot * 512 + lane * 8) = *(short8*)v;
  } else if (blk < kB0B) {            // ---- degree
    int e = (blk - kB0G) * 256 + t;
    if (e < kE) atomicAdd(&deg[ei[kE + e]], 1.f);
  } else {                            // ---- per-graph bounds (batch sorted)
    if (t > kB) return;
    int lo = 0, hi = kN;
    while (lo < hi) { int mid = (lo + hi) >> 1; if (batch[mid] < t) lo = mid + 1; else hi = mid; }
    start[t] = lo;
  }
}

// ============ CSR build: scan (1 block) + scatter ============
__global__ __launch_bounds__(256) void k_csr(const float* __restrict__ deg,
                                             int* __restrict__ ptr) {
  __shared__ int ps[256];
  int t = threadIdx.x;
  int base = t * 40;                       // 256*40 = 10240 >= kN
  int s = 0;
#pragma unroll 8
  for (int j = 0; j < 40; ++j) {
    int n = base + j;
    if (n < kN) s += (int)deg[n];
  }
  ps[t] = s;
  __syncthreads();
  for (int off = 1; off < 256; off <<= 1) {
    int v = (t >= off) ? ps[t - off] : 0;
    __syncthreads();
    ps[t] += v;
    __syncthreads();
  }
  int run = ps[t] - s;                     // exclusive prefix of this chunk
  for (int j = 0; j < 40; ++j) {
    int n = base + j;
    if (n < kN) { ptr[n] = run; run += (int)deg[n]; }
  }
  if (t == 255) ptr[kN] = ps[255];
}

__global__ __launch_bounds__(256) void k_scatter(const int* __restrict__ ei,
    const int* __restrict__ ptr, int* __restrict__ cnt, int* __restrict__ csr) {
  int e = blockIdx.x * 256 + threadIdx.x;
  if (e < kE) {
    int d = ei[kE + e];
    int pos = atomicAdd(&cnt[d], 1);
    csr[ptr[d] + pos] = e;
  }
}

// ============ message GEMM v7 ============
// Grid (392, 2): block = 64 edges x 64 f x K-half (by: h in [by*64, by*64+64)).
// 4 waves K-split (16 h each). Wave tile M=64 (2 mf) x N=64 (2 nf): A built ONCE
// feeds 4 MFMAs. Partials -> per-wave LDS region -> block reduce -> plain stores
// to the by-selected partial msg buffer. No atomics anywhere.
__global__ __launch_bounds__(256) void k_msg7(const int* __restrict__ ei,
    const float* __restrict__ outn, const unsigned short* __restrict__ hid7,
    const unsigned short* __restrict__ Bc2,
    float* __restrict__ msg0, float* __restrict__ msg1) {
  __shared__ __align__(16) unsigned short hidS[64 * 64];    // [h_loc][e_loc], 8 KB
  __shared__ __align__(16) float res[4][64 * 64];           // per-wave [e64][f64], 64 KB
  const int t = threadIdx.x, lane = t & 63, wave = t >> 6;
  const int er = lane & 31, hi5 = lane >> 5;
  const int grp = blockIdx.x, by = blockIdx.y, e0 = grp * 64;
  float* __restrict__ msgP = by ? msg1 : msg0;
  {   // stage hid K-half tile (8 KB linear): hid7 + grp*8192 + by*4096
    const char* hsrc = (const char*)(hid7 + (size_t)grp * 8192 + by * 4096);
#pragma unroll
    for (int i = 0; i < 2; ++i) {
      int off = (wave * 2 + i) * 1024 + lane * 16;
      __builtin_amdgcn_global_load_lds(
          (const __attribute__((address_space(1))) void*)(hsrc + off),
          (__attribute__((address_space(3))) void*)((char*)hidS + off), 16, 0, 0);
    }
  }
  // B prefetch: one h (8 slots: 4 db x 2 nf) in flight
  const int hg0 = by * 64 + wave * 16;                  // wave's first global h
  const unsigned short* bp = Bc2 + (size_t)(hg0 * 8) * 512 + lane * 8;
  short8 bvr[8];
#pragma unroll
  for (int j = 0; j < 8; ++j) bvr[j] = *(const short8*)(bp + (size_t)j * 512);
  // gather out[src] rows: 2 mf x 4 db x 2 quads (64 VGPR)
  floatx4 o[2][4][2];
#pragma unroll
  for (int mf = 0; mf < 2; ++mf) {
    int e = e0 + mf * 32 + er;
    int s = (e < kE) ? ei[e] : 0;
    const float* base = outn + (size_t)s * 64 + hi5 * 8;
#pragma unroll
    for (int db = 0; db < 4; ++db) {
      o[mf][db][0] = *(const floatx4*)(base + db * 16);
      o[mf][db][1] = *(const floatx4*)(base + db * 16 + 4);
    }
  }
  __syncthreads();   // hidS ready

  floatx16 acc[2][2];
#pragma unroll
  for (int mf = 0; mf < 2; ++mf)
#pragma unroll
    for (int nf = 0; nf < 2; ++nf)
#pragma unroll
      for (int i = 0; i < 16; ++i) acc[mf][nf][i] = 0.f;

  const int hl0 = wave * 16;
#pragma unroll 2
  for (int hh = 0; hh < 16; ++hh) {
    int hl = hl0 + hh;
    float hv0 = __uint_as_float(((unsigned)hidS[hl * 64 + er]) << 16);
    float hv1 = __uint_as_float(((unsigned)hidS[hl * 64 + 32 + er]) << 16);
    const unsigned short* bpn = bp + (size_t)((hh + 1) * 8) * 512;   // next h (max slot 1031: in-bounds)
#pragma unroll
    for (int db = 0; db < 4; ++db) {
      short8 bv0 = bvr[db * 2], bv1 = bvr[db * 2 + 1];
      bvr[db * 2]     = *(const short8*)(bpn + (size_t)(db * 2) * 512);
      bvr[db * 2 + 1] = *(const short8*)(bpn + (size_t)(db * 2 + 1) * 512);
      union { uint4 u; short8 s; } U0, U1;
      floatx4 a0 = o[0][db][0] * hv0, b0 = o[0][db][1] * hv0;
      floatx4 a1 = o[1][db][0] * hv1, b1 = o[1][db][1] * hv1;
      U0.u.x = cvtpk(a0.x, a0.y); U0.u.y = cvtpk(a0.z, a0.w);
      U0.u.z = cvtpk(b0.x, b0.y); U0.u.w = cvtpk(b0.z, b0.w);
      U1.u.x = cvtpk(a1.x, a1.y); U1.u.y = cvtpk(a1.z, a1.w);
      U1.u.z = cvtpk(b1.x, b1.y); U1.u.w = cvtpk(b1.z, b1.w);
      acc[0][0] = __builtin_amdgcn_mfma_f32_32x32x16_bf16(U0.s, bv0, acc[0][0], 0, 0, 0);
      acc[0][1] = __builtin_amdgcn_mfma_f32_32x32x16_bf16(U0.s, bv1, acc[0][1], 0, 0, 0);
      acc[1][0] = __builtin_amdgcn_mfma_f32_32x32x16_bf16(U1.s, bv0, acc[1][0], 0, 0, 0);
      acc[1][1] = __builtin_amdgcn_mfma_f32_32x32x16_bf16(U1.s, bv1, acc[1][1], 0, 0, 0);
    }
  }
  if (by == 1 && wave == 3) {   // bias: msg += out @ reshape(be2,64,64), added once
#pragma unroll
    for (int db = 0; db < 4; ++db) {
      short8 bv0 = *(const short8*)(Bc2 + (size_t)(1024 + db * 2) * 512 + lane * 8);
      short8 bv1 = *(const short8*)(Bc2 + (size_t)(1024 + db * 2 + 1) * 512 + lane * 8);
      union { uint4 u; short8 s; } U0, U1;
      floatx4 a0 = o[0][db][0], b0 = o[0][db][1];
      floatx4 a1 = o[1][db][0], b1 = o[1][db][1];
      U0.u.x = cvtpk(a0.x, a0.y); U0.u.y = cvtpk(a0.z, a0.w);
      U0.u.z = cvtpk(b0.x, b0.y); U0.u.w = cvtpk(b0.z, b0.w);
      U1.u.x = cvtpk(a1.x, a1.y); U1.u.y = cvtpk(a1.z, a1.w);
      U1.u.z = cvtpk(b1.x, b1.y); U1.u.w = cvtpk(b1.z, b1.w);
      acc[0][0] = __builtin_amdgcn_mfma_f32_32x32x16_bf16(U0.s, bv0, acc[0][0], 0, 0, 0);
      acc[0][1] = __builtin_amdgcn_mfma_f32_32x32x16_bf16(U0.s, bv1, acc[0][1], 0, 0, 0);
      acc[1][0] = __builtin_amdgcn_mfma_f32_32x32x16_bf16(U1.s, bv0, acc[1][0], 0, 0, 0);
      acc[1][1] = __builtin_amdgcn_mfma_f32_32x32x16_bf16(U1.s, bv1, acc[1][1], 0, 0, 0);
    }
  }
  // write K-partials to this wave's private region (plain ds_write, 2-way-free banks)
#pragma unroll
  for (int mf = 0; mf < 2; ++mf)
#pragma unroll
    for (int nf = 0; nf < 2; ++nf)
#pragma unroll
      for (int reg = 0; reg < 16; ++reg) {
        int row = (reg & 3) + 8 * (reg >> 2) + 4 * hi5 + mf * 32;
        res[wave][row * 64 + nf * 32 + er] = acc[mf][nf][reg];
      }
  __syncthreads();
  // block reduce (4 partials) + plain coalesced stores (stride-16B lanes: conflict-free)
#pragma unroll
  for (int q = 0; q < 4; ++q) {
    int idx = q * 1024 + t * 4;
    float4 s4 = *(const float4*)&res[0][idx];
#pragma unroll
    for (int w = 1; w < 4; ++w) {
      float4 a4 = *(const float4*)&res[w][idx];
      s4.x += a4.x; s4.y += a4.y; s4.z += a4.z; s4.w += a4.w;
    }
    int e = e0 + (idx >> 6);
    if (e < kE) *(float4*)(msgP + (size_t)e * 64 + (idx & 63)) = s4;
  }
}

// ============ NNConv-combine + GRU cell; CSR gather of 2 K-half partials ============
__global__ __launch_bounds__(256) void k_update(const float* __restrict__ msg0,
    const float* __restrict__ msg1, const int* __restrict__ ptr,
    const int* __restrict__ csr, const float* __restrict__ deg,
    const float* __restrict__ root, const float* __restrict__ convb,
    const float* __restrict__ Wi, const float* __restrict__ bi,
    const float* __restrict__ Wh, const float* __restrict__ bh,
    float* __restrict__ out) {
  __shared__ float sh_out[16][64];
  __shared__ float sh_m[16][64];
  int t = threadIdx.x, lane = t & 63, w = t >> 6;
  int nb = blockIdx.x * 16;
#pragma unroll
  for (int i = 0; i < 4; ++i) {
    int idx = t + i * 256;
    sh_out[idx >> 6][idx & 63] = out[(size_t)(nb + (idx >> 6)) * 64 + (idx & 63)];
  }
  __syncthreads();
  int n0 = w * 4;
  float acc[4];
#pragma unroll
  for (int i = 0; i < 4; ++i) {
    int n = nb + n0 + i;
    float dg = fmaxf(deg[n], 1.f);
    float s = 0.f;
    int p0 = ptr[n], p1 = ptr[n + 1];
    for (int k = p0; k < p1; ++k) {
      size_t off2 = (size_t)csr[k] * 64 + lane;
      s += msg0[off2] + msg1[off2];
    }
    acc[i] = s / dg + convb[lane];
  }
  for (int d = 0; d < 64; ++d) {
    float rv = root[d * 64 + lane];
#pragma unroll
    for (int i = 0; i < 4; ++i) acc[i] += sh_out[n0 + i][d] * rv;
  }
#pragma unroll
  for (int i = 0; i < 4; ++i) sh_m[n0 + i][lane] = fmaxf(acc[i], 0.f);
  __syncthreads();
  float ir[4] = {}, iz[4] = {}, ig[4] = {}, hr[4] = {}, hz[4] = {}, hg[4] = {};
  for (int d = 0; d < 64; ++d) {
    float wi0 = Wi[d * 192 + lane], wi1 = Wi[d * 192 + 64 + lane], wi2 = Wi[d * 192 + 128 + lane];
    float wh0 = Wh[d * 192 + lane], wh1 = Wh[d * 192 + 64 + lane], wh2 = Wh[d * 192 + 128 + lane];
#pragma unroll
    for (int i = 0; i < 4; ++i) {
      float mv = sh_m[n0 + i][d], hv = sh_out[n0 + i][d];
      ir[i] += mv * wi0; iz[i] += mv * wi1; ig[i] += mv * wi2;
      hr[i] += hv * wh0; hz[i] += hv * wh1; hg[i] += hv * wh2;
    }
  }
  float bi0 = bi[lane], bi1 = bi[64 + lane], bi2 = bi[128 + lane];
  float bh0 = bh[lane], bh1 = bh[64 + lane], bh2 = bh[128 + lane];
#pragma unroll
  for (int i = 0; i < 4; ++i) {
    float r = sigmf(ir[i] + bi0 + hr[i] + bh0);
    float z = sigmf(iz[i] + bi1 + hz[i] + bh1);
    float nn = tanh_(ig[i] + bi2 + r * (hg[i] + bh2));
    float h = sh_out[n0 + i][lane];
    out[(size_t)(nb + n0 + i) * 64 + lane] = (1.f - z) * nn + z * h;
  }
}

// ============ all 3 Set2Set steps + head1 in one kernel (block = graph) ============
__global__ __launch_bounds__(256) void k_s2s3(const float* __restrict__ out,
    const int* __restrict__ start, const float* __restrict__ Wli,
    const float* __restrict__ bli, const float* __restrict__ Wlh,
    const float* __restrict__ blh, const float* __restrict__ Wr1,
    const float* __restrict__ br1, float* __restrict__ y1) {
  __shared__ float qs[128], hls[64], cls[64], gates[256];
  __shared__ float ebuf[1024];
  __shared__ float part[4][64];
  __shared__ float sred[8];
  int b = blockIdx.x, t = threadIdx.x, lane = t & 63, w = t >> 6;
  if (t < 128) qs[t] = 0.f;
  if (t < 64) { hls[t] = 0.f; cls[t] = 0.f; }
  int s0 = start[b], s1 = start[b + 1];
  int cnt = s1 - s0; if (cnt > 1024) cnt = 1024;
  __syncthreads();
  for (int it = 0; it < 3; ++it) {
    float g = bli[t] + blh[t];
    for (int j = 0; j < 128; ++j) g += qs[j] * Wli[j * 256 + t];
    for (int j = 0; j < 64; ++j) g += hls[j] * Wlh[j * 256 + t];
    gates[t] = g;
    __syncthreads();
    if (t < 64) {                      // gate order i, f, g, o
      float ig = sigmf(gates[t]), fg = sigmf(gates[64 + t]);
      float gg = tanh_(gates[128 + t]), og = sigmf(gates[192 + t]);
      float c = fg * cls[t] + ig * gg;
      float h = og * tanh_(c);
      cls[t] = c; hls[t] = h;
      qs[t] = h;                       // q part of q_star
    }
    __syncthreads();
    for (int idx = w; idx < cnt; idx += 4) {           // e[n] = <out[n], q>
      int node = s0 + idx;
      float p = out[(size_t)node * 64 + lane] * hls[lane];
#pragma unroll
      for (int m = 1; m < 64; m <<= 1) p += __shfl_xor(p, m, 64);
      if (lane == 0) ebuf[idx] = p;
    }
    __syncthreads();
    float mx = -3.4e38f;
    for (int idx = t; idx < cnt; idx += 256) mx = fmaxf(mx, ebuf[idx]);
#pragma unroll
    for (int m = 1; m < 64; m <<= 1) mx = fmaxf(mx, __shfl_xor(mx, m, 64));
    if (lane == 0) sred[w] = mx;
    __syncthreads();
    mx = fmaxf(fmaxf(sred[0], sred[1]), fmaxf(sred[2], sred[3]));
    float s = 0.f;
    for (int idx = t; idx < cnt; idx += 256) {
      float a = __expf(ebuf[idx] - mx);
      ebuf[idx] = a; s += a;
    }
#pragma unroll
    for (int m = 1; m < 64; m <<= 1) s += __shfl_xor(s, m, 64);
    if (lane == 0) sred[4 + w] = s;
    __syncthreads();
    s = sred[4] + sred[5] + sred[6] + sred[7];
    float rs = 1.f / fmaxf(s, 1e-12f);
    float pr = 0.f;
    for (int idx = w; idx < cnt; idx += 4) {
      int node = s0 + idx;
      pr += ebuf[idx] * out[(size_t)node * 64 + lane];
    }
    part[w][lane] = pr;
    __syncthreads();
    if (t < 64)
      qs[64 + t] = (part[0][t] + part[1][t] + part[2][t] + part[3][t]) * rs;
    __syncthreads();
  }
  if (t < 64) {                        // head1: y1 = q_star @ Wr1 + br1
    float acc = br1[t];
    for (int j = 0; j < 128; ++j) acc += qs[j] * Wr1[j * 64 + t];
    y1[b * 64 + t] = acc;
  }
}

// ============ head2: BatchNorm (batch stats) + relu + Wr2 ============
__global__ __launch_bounds__(256) void k_head2(const float* __restrict__ y1,
    const float* __restrict__ gamma, const float* __restrict__ beta,
    const float* __restrict__ Wr2, const float* __restrict__ br2,
    float* __restrict__ outp) {
  __shared__ float mu[64], ri[64];
  int t = threadIdx.x;
  if (t < 64) {
    float s1 = 0.f, s2 = 0.f;
    for (int b = 0; b < kB; ++b) { float v = y1[b * 64 + t]; s1 += v; s2 += v * v; }
    float m = s1 / (float)kB;
    mu[t] = m; ri[t] = rsqrtf(s2 / (float)kB - m * m + 1e-5f);
  }
  __syncthreads();
  if (t < kB) {
    float acc = br2[0];
    for (int f = 0; f < 64; ++f) {
      float v = (y1[t * 64 + f] - mu[f]) * ri[f] * gamma[f] + beta[f];
      acc += fmaxf(v, 0.f) * Wr2[f];
    }
    outp[t] = acc;
  }
}

extern "C" void kernel_launch(void* const* d_in, const int* in_sizes, int n_in,
                              void* d_out, int out_size, void* d_ws, size_t ws_size,
                              hipStream_t stream) {
  const float* x     = (const float*)d_in[0];
  const int*   ei    = (const int*)d_in[1];
  const float* ea    = (const float*)d_in[2];
  const int*   batch = (const int*)d_in[3];
  const float* W0    = (const float*)d_in[4];
  const float* b0    = (const float*)d_in[5];
  const float* We1   = (const float*)d_in[6];
  const float* be1   = (const float*)d_in[7];
  const float* We2   = (const float*)d_in[8];
  const float* be2   = (const float*)d_in[9];
  const float* root  = (const float*)d_in[10];
  const float* convb = (const float*)d_in[11];
  const float* Wi    = (const float*)d_in[12];
  const float* bi    = (const float*)d_in[13];
  const float* Wh    = (const float*)d_in[14];
  const float* bh    = (const float*)d_in[15];
  const float* Wli   = (const float*)d_in[16];
  const float* bli   = (const float*)d_in[17];
  const float* Wlh   = (const float*)d_in[18];
  const float* blh   = (const float*)d_in[19];
  const float* Wr1   = (const float*)d_in[20];
  const float* br1   = (const float*)d_in[21];
  const float* gamma = (const float*)d_in[22];
  const float* beta  = (const float*)d_in[23];
  const float* Wr2   = (const float*)d_in[24];
  const float* br2   = (const float*)d_in[25];
  (void)in_sizes; (void)n_in; (void)out_size; (void)ws_size;

  char* ws = (char*)d_ws;
  size_t off = 0;
  auto take = [&](size_t bytes) {
    char* p = ws + off;
    off += (bytes + 255) & ~(size_t)255;
    return p;
  };
  // zero-region: deg + cnt (contiguous, one memset)
  float* deg  = (float*)take((size_t)kN * 4);
  int*   cnt  = (int*)take((size_t)kN * 4);
  size_t zeroBytes = off;
  int*   ptr   = (int*)take((size_t)(kN + 1) * 4);
  int*   csr   = (int*)take((size_t)kE * 4);
  int*   start = (int*)take(256 * 4);
  float* outn  = (float*)take((size_t)kN * kD * 4);
  float* msg0  = (float*)take((size_t)kEPad * kD * 4);                     // 6.4 MB
  float* msg1  = (float*)take((size_t)kEPad * kD * 4);                     // 6.4 MB
  unsigned short* hid7 = (unsigned short*)take((size_t)kGrp * 8192 * 2);   // 6.4 MB
  unsigned short* Bc2  = (unsigned short*)take((size_t)1032 * 512 * 2);    // 1.03 MB
  float* y1    = (float*)take((size_t)kB * 64 * 4);

  hipMemsetAsync(deg, 0, zeroBytes, stream);
  k_setup<<<kBlkSetup, 256, 0, stream>>>(x, W0, b0, ea, We1, be1, We2, be2, ei, batch,
                                         outn, hid7, Bc2, deg, start);
  k_csr<<<1, 256, 0, stream>>>(deg, ptr);
  k_scatter<<<(kE + 255) / 256, 256, 0, stream>>>(ei, ptr, cnt, csr);
  dim3 gm(kGrp, 2);
  for (int s = 0; s < 3; ++s) {
    k_msg7<<<gm, 256, 0, stream>>>(ei, outn, hid7, Bc2, msg0, msg1);
    k_update<<<kN / 16, 256, 0, stream>>>(msg0, msg1, ptr, csr, deg, root, convb,
                                          Wi, bi, Wh, bh, outn);
  }
  k_s2s3<<<kB, 256, 0, stream>>>(outn, start, Wli, bli, Wlh, blh, Wr1, br1, y1);
  k_head2<<<1, 256, 0, stream>>>(y1, gamma, beta, Wr2, br2, (float*)d_out);
}

// Round 8
// 284.535 us; speedup vs baseline: 3.0220x; 1.0749x over previous
//
#include <hip/hip_runtime.h>
#include <hip/hip_bf16.h>

constexpr int kN = 10000;
constexpr int kE = 25000;
constexpr int kB = 128;
constexpr int kNF = 32;
constexpr int kEF = 8;
constexpr int kD = 64;
constexpr int kGrp = 392;          // 64-edge groups (25088 padded)
constexpr int kEPad = kGrp * 64;   // 25088
constexpr int kNCap = 320;         // s2s LDS node cap (global fallback beyond)

typedef __attribute__((ext_vector_type(8))) short short8;
typedef __attribute__((ext_vector_type(4))) float floatx4;
typedef __attribute__((ext_vector_type(16))) float floatx16;

__device__ __forceinline__ unsigned short f2bf(float f) {
  unsigned u = __float_as_uint(f);
  u = (u + 0x7fffu + ((u >> 16) & 1u)) >> 16;   // RNE
  return (unsigned short)u;
}
__device__ __forceinline__ float sigmf(float x) { return 1.f / (1.f + __expf(-x)); }
__device__ __forceinline__ float tanh_(float x) { return 1.f - 2.f / (__expf(2.f * x) + 1.f); }

__device__ __forceinline__ unsigned cvtpk(float lo, float hi) {
  unsigned r;
  asm("v_cvt_pk_bf16_f32 %0, %1, %2" : "=v"(r) : "v"(lo), "v"(hi));
  return r;
}

// ============ fused setup: dense0 | hidden([grp][h128][e64]) | prep_b | deg | bounds ====
constexpr int kBlkDense = 2500;                 // kN*64/256
constexpr int kBlkHid   = 12544;                // 392*128*64/256
constexpr int kBlkPrep  = 258;                  // 1032 slots * 64 lanes / 256
constexpr int kBlkDeg   = 98;
constexpr int kB0H = kBlkDense;                 // 2500
constexpr int kB0P = kB0H + kBlkHid;            // 15044
constexpr int kB0G = kB0P + kBlkPrep;           // 15302
constexpr int kB0B = kB0G + kBlkDeg;            // 15400
constexpr int kBlkSetup = kB0B + 1;             // 15401

__global__ __launch_bounds__(256) void k_setup(
    const float* __restrict__ x, const float* __restrict__ W0, const float* __restrict__ b0,
    const float* __restrict__ ea, const float* __restrict__ We1, const float* __restrict__ be1,
    const float* __restrict__ We2, const float* __restrict__ be2,
    const int* __restrict__ ei, const int* __restrict__ batch,
    float* __restrict__ outn, unsigned short* __restrict__ hid7,
    unsigned short* __restrict__ Bc2, float* __restrict__ deg, int* __restrict__ start) {
  const int blk = blockIdx.x, t = threadIdx.x;
  if (blk < kB0H) {                   // ---- dense0: out = relu(x@W0+b0), [N,64]
    int gid = blk * 256 + t;
    int n = gid >> 6, f = gid & 63;
    float acc = b0[f];
    const float* xr = x + n * kNF;
#pragma unroll
    for (int j = 0; j < kNF; ++j) acc += xr[j] * W0[j * kD + f];
    outn[gid] = fmaxf(acc, 0.f);
  } else if (blk < kB0P) {            // ---- hidden: hid7[grp][h 128][e 64]
    int gid = (blk - kB0H) * 256 + t;
    int e_loc = gid & 63, h = (gid >> 6) & 127, grp = gid >> 13;
    int e = grp * 64 + e_loc;
    float r = 0.f;
    if (e < kE) {
      float acc = be1[h];
      const float* er = ea + e * kEF;
#pragma unroll
      for (int j = 0; j < kEF; ++j) acc += er[j] * We1[j * 128 + h];
      r = fmaxf(acc, 0.f);
    }
    hid7[gid] = f2bf(r);
  } else if (blk < kB0G) {            // ---- prep B: fragment-major Bc2 (32x32x16)
    int lg = (blk - kB0P) * 256 + t;
    int lane = lg & 63, slot = lg >> 6;            // slot 0..1031
    int fcol, dbase;
    const float* srcmat;
    if (slot < 1024) {
      int nf_ = slot & 1, hdb = slot >> 1;         // slot = (h*4+db)*2+nf
      int db = hdb & 3, h = hdb >> 2;
      fcol = nf_ * 32 + (lane & 31);
      dbase = db * 16 + (lane >> 5) * 8;
      srcmat = We2 + (size_t)h * 4096;
    } else {
      int s = slot - 1024;
      int db = s >> 1, nf_ = s & 1;
      fcol = nf_ * 32 + (lane & 31);
      dbase = db * 16 + (lane >> 5) * 8;
      srcmat = be2;
    }
    unsigned short v[8];
#pragma unroll
    for (int j = 0; j < 8; ++j) v[j] = f2bf(srcmat[(size_t)(dbase + j) * 64 + fcol]);
    *(short8*)(Bc2 + (size_t)slot * 512 + lane * 8) = *(short8*)v;
  } else if (blk < kB0B) {            // ---- degree
    int e = (blk - kB0G) * 256 + t;
    if (e < kE) atomicAdd(&deg[ei[kE + e]], 1.f);
  } else {                            // ---- per-graph bounds (batch sorted)
    if (t > kB) return;
    int lo = 0, hi = kN;
    while (lo < hi) { int mid = (lo + hi) >> 1; if (batch[mid] < t) lo = mid + 1; else hi = mid; }
    start[t] = lo;
  }
}

// ============ CSR build: scan (1 block) + scatter ============
__global__ __launch_bounds__(256) void k_csr(const float* __restrict__ deg,
                                             int* __restrict__ ptr) {
  __shared__ int ps[256];
  int t = threadIdx.x;
  int base = t * 40;                       // 256*40 = 10240 >= kN
  int s = 0;
#pragma unroll 8
  for (int j = 0; j < 40; ++j) {
    int n = base + j;
    if (n < kN) s += (int)deg[n];
  }
  ps[t] = s;
  __syncthreads();
  for (int off = 1; off < 256; off <<= 1) {
    int v = (t >= off) ? ps[t - off] : 0;
    __syncthreads();
    ps[t] += v;
    __syncthreads();
  }
  int run = ps[t] - s;                     // exclusive prefix of this chunk
  for (int j = 0; j < 40; ++j) {
    int n = base + j;
    if (n < kN) { ptr[n] = run; run += (int)deg[n]; }
  }
  if (t == 255) ptr[kN] = ps[255];
}

__global__ __launch_bounds__(256) void k_scatter(const int* __restrict__ ei,
    const int* __restrict__ ptr, int* __restrict__ cnt, int* __restrict__ csr) {
  int e = blockIdx.x * 256 + threadIdx.x;
  if (e < kE) {
    int d = ei[kE + e];
    int pos = atomicAdd(&cnt[d], 1);
    csr[ptr[d] + pos] = e;
  }
}

// ============ message GEMM v7 ============
// Grid (392, 2): block = 64 edges x 64 f x K-half (by: h in [by*64, by*64+64)).
// 4 waves K-split (16 h each). Wave tile M=64 (2 mf) x N=64 (2 nf): A built ONCE
// feeds 4 MFMAs. Partials -> per-wave LDS region -> block reduce -> plain stores
// to the by-selected partial msg buffer. No atomics anywhere.
__global__ __launch_bounds__(256) void k_msg7(const int* __restrict__ ei,
    const float* __restrict__ outn, const unsigned short* __restrict__ hid7,
    const unsigned short* __restrict__ Bc2,
    float* __restrict__ msg0, float* __restrict__ msg1) {
  __shared__ __align__(16) unsigned short hidS[64 * 64];    // [h_loc][e_loc], 8 KB
  __shared__ __align__(16) float res[4][64 * 64];           // per-wave [e64][f64], 64 KB
  const int t = threadIdx.x, lane = t & 63, wave = t >> 6;
  const int er = lane & 31, hi5 = lane >> 5;
  const int grp = blockIdx.x, by = blockIdx.y, e0 = grp * 64;
  float* __restrict__ msgP = by ? msg1 : msg0;
  {   // stage hid K-half tile (8 KB linear): hid7 + grp*8192 + by*4096
    const char* hsrc = (const char*)(hid7 + (size_t)grp * 8192 + by * 4096);
#pragma unroll
    for (int i = 0; i < 2; ++i) {
      int off = (wave * 2 + i) * 1024 + lane * 16;
      __builtin_amdgcn_global_load_lds(
          (const __attribute__((address_space(1))) void*)(hsrc + off),
          (__attribute__((address_space(3))) void*)((char*)hidS + off), 16, 0, 0);
    }
  }
  // B prefetch: one h (8 slots: 4 db x 2 nf) in flight
  const int hg0 = by * 64 + wave * 16;                  // wave's first global h
  const unsigned short* bp = Bc2 + (size_t)(hg0 * 8) * 512 + lane * 8;
  short8 bvr[8];
#pragma unroll
  for (int j = 0; j < 8; ++j) bvr[j] = *(const short8*)(bp + (size_t)j * 512);
  // gather out[src] rows: 2 mf x 4 db x 2 quads (64 VGPR)
  floatx4 o[2][4][2];
#pragma unroll
  for (int mf = 0; mf < 2; ++mf) {
    int e = e0 + mf * 32 + er;
    int s = (e < kE) ? ei[e] : 0;
    const float* base = outn + (size_t)s * 64 + hi5 * 8;
#pragma unroll
    for (int db = 0; db < 4; ++db) {
      o[mf][db][0] = *(const floatx4*)(base + db * 16);
      o[mf][db][1] = *(const floatx4*)(base + db * 16 + 4);
    }
  }
  __syncthreads();   // hidS ready

  floatx16 acc[2][2];
#pragma unroll
  for (int mf = 0; mf < 2; ++mf)
#pragma unroll
    for (int nf = 0; nf < 2; ++nf)
#pragma unroll
      for (int i = 0; i < 16; ++i) acc[mf][nf][i] = 0.f;

  const int hl0 = wave * 16;
#pragma unroll 2
  for (int hh = 0; hh < 16; ++hh) {
    int hl = hl0 + hh;
    float hv0 = __uint_as_float(((unsigned)hidS[hl * 64 + er]) << 16);
    float hv1 = __uint_as_float(((unsigned)hidS[hl * 64 + 32 + er]) << 16);
    const unsigned short* bpn = bp + (size_t)((hh + 1) * 8) * 512;   // next h (max slot 1031: in-bounds)
#pragma unroll
    for (int db = 0; db < 4; ++db) {
      short8 bv0 = bvr[db * 2], bv1 = bvr[db * 2 + 1];
      bvr[db * 2]     = *(const short8*)(bpn + (size_t)(db * 2) * 512);
      bvr[db * 2 + 1] = *(const short8*)(bpn + (size_t)(db * 2 + 1) * 512);
      union { uint4 u; short8 s; } U0, U1;
      floatx4 a0 = o[0][db][0] * hv0, b0 = o[0][db][1] * hv0;
      floatx4 a1 = o[1][db][0] * hv1, b1 = o[1][db][1] * hv1;
      U0.u.x = cvtpk(a0.x, a0.y); U0.u.y = cvtpk(a0.z, a0.w);
      U0.u.z = cvtpk(b0.x, b0.y); U0.u.w = cvtpk(b0.z, b0.w);
      U1.u.x = cvtpk(a1.x, a1.y); U1.u.y = cvtpk(a1.z, a1.w);
      U1.u.z = cvtpk(b1.x, b1.y); U1.u.w = cvtpk(b1.z, b1.w);
      acc[0][0] = __builtin_amdgcn_mfma_f32_32x32x16_bf16(U0.s, bv0, acc[0][0], 0, 0, 0);
      acc[0][1] = __builtin_amdgcn_mfma_f32_32x32x16_bf16(U0.s, bv1, acc[0][1], 0, 0, 0);
      acc[1][0] = __builtin_amdgcn_mfma_f32_32x32x16_bf16(U1.s, bv0, acc[1][0], 0, 0, 0);
      acc[1][1] = __builtin_amdgcn_mfma_f32_32x32x16_bf16(U1.s, bv1, acc[1][1], 0, 0, 0);
    }
  }
  if (by == 1 && wave == 3) {   // bias: msg += out @ reshape(be2,64,64), added once
#pragma unroll
    for (int db = 0; db < 4; ++db) {
      short8 bv0 = *(const short8*)(Bc2 + (size_t)(1024 + db * 2) * 512 + lane * 8);
      short8 bv1 = *(const short8*)(Bc2 + (size_t)(1024 + db * 2 + 1) * 512 + lane * 8);
      union { uint4 u; short8 s; } U0, U1;
      floatx4 a0 = o[0][db][0], b0 = o[0][db][1];
      floatx4 a1 = o[1][db][0], b1 = o[1][db][1];
      U0.u.x = cvtpk(a0.x, a0.y); U0.u.y = cvtpk(a0.z, a0.w);
      U0.u.z = cvtpk(b0.x, b0.y); U0.u.w = cvtpk(b0.z, b0.w);
      U1.u.x = cvtpk(a1.x, a1.y); U1.u.y = cvtpk(a1.z, a1.w);
      U1.u.z = cvtpk(b1.x, b1.y); U1.u.w = cvtpk(b1.z, b1.w);
      acc[0][0] = __builtin_amdgcn_mfma_f32_32x32x16_bf16(U0.s, bv0, acc[0][0], 0, 0, 0);
      acc[0][1] = __builtin_amdgcn_mfma_f32_32x32x16_bf16(U0.s, bv1, acc[0][1], 0, 0, 0);
      acc[1][0] = __builtin_amdgcn_mfma_f32_32x32x16_bf16(U1.s, bv0, acc[1][0], 0, 0, 0);
      acc[1][1] = __builtin_amdgcn_mfma_f32_32x32x16_bf16(U1.s, bv1, acc[1][1], 0, 0, 0);
    }
  }
  // write K-partials to this wave's private region (plain ds_write, 2-way-free banks)
#pragma unroll
  for (int mf = 0; mf < 2; ++mf)
#pragma unroll
    for (int nf = 0; nf < 2; ++nf)
#pragma unroll
      for (int reg = 0; reg < 16; ++reg) {
        int row = (reg & 3) + 8 * (reg >> 2) + 4 * hi5 + mf * 32;
        res[wave][row * 64 + nf * 32 + er] = acc[mf][nf][reg];
      }
  __syncthreads();
  // block reduce (4 partials) + plain coalesced stores (stride-16B lanes: conflict-free)
#pragma unroll
  for (int q = 0; q < 4; ++q) {
    int idx = q * 1024 + t * 4;
    float4 s4 = *(const float4*)&res[0][idx];
#pragma unroll
    for (int w = 1; w < 4; ++w) {
      float4 a4 = *(const float4*)&res[w][idx];
      s4.x += a4.x; s4.y += a4.y; s4.z += a4.z; s4.w += a4.w;
    }
    int e = e0 + (idx >> 6);
    if (e < kE) *(float4*)(msgP + (size_t)e * 64 + (idx & 63)) = s4;
  }
}

// ============ NNConv-combine + GRU cell; CSR gather of 2 K-half partials ============
__global__ __launch_bounds__(256) void k_update(const float* __restrict__ msg0,
    const float* __restrict__ msg1, const int* __restrict__ ptr,
    const int* __restrict__ csr, const float* __restrict__ deg,
    const float* __restrict__ root, const float* __restrict__ convb,
    const float* __restrict__ Wi, const float* __restrict__ bi,
    const float* __restrict__ Wh, const float* __restrict__ bh,
    float* __restrict__ out) {
  __shared__ float sh_out[16][64];
  __shared__ float sh_m[16][64];
  int t = threadIdx.x, lane = t & 63, w = t >> 6;
  int nb = blockIdx.x * 16;
#pragma unroll
  for (int i = 0; i < 4; ++i) {
    int idx = t + i * 256;
    sh_out[idx >> 6][idx & 63] = out[(size_t)(nb + (idx >> 6)) * 64 + (idx & 63)];
  }
  __syncthreads();
  int n0 = w * 4;
  float acc[4];
#pragma unroll
  for (int i = 0; i < 4; ++i) {
    int n = nb + n0 + i;
    float dg = fmaxf(deg[n], 1.f);
    float s = 0.f;
    int p0 = ptr[n], p1 = ptr[n + 1];
    for (int k = p0; k < p1; ++k) {
      size_t off2 = (size_t)csr[k] * 64 + lane;
      s += msg0[off2] + msg1[off2];
    }
    acc[i] = s / dg + convb[lane];
  }
  for (int d = 0; d < 64; ++d) {
    float rv = root[d * 64 + lane];
#pragma unroll
    for (int i = 0; i < 4; ++i) acc[i] += sh_out[n0 + i][d] * rv;
  }
#pragma unroll
  for (int i = 0; i < 4; ++i) sh_m[n0 + i][lane] = fmaxf(acc[i], 0.f);
  __syncthreads();
  float ir[4] = {}, iz[4] = {}, ig[4] = {}, hr[4] = {}, hz[4] = {}, hg[4] = {};
  for (int d = 0; d < 64; ++d) {
    float wi0 = Wi[d * 192 + lane], wi1 = Wi[d * 192 + 64 + lane], wi2 = Wi[d * 192 + 128 + lane];
    float wh0 = Wh[d * 192 + lane], wh1 = Wh[d * 192 + 64 + lane], wh2 = Wh[d * 192 + 128 + lane];
#pragma unroll
    for (int i = 0; i < 4; ++i) {
      float mv = sh_m[n0 + i][d], hv = sh_out[n0 + i][d];
      ir[i] += mv * wi0; iz[i] += mv * wi1; ig[i] += mv * wi2;
      hr[i] += hv * wh0; hz[i] += hv * wh1; hg[i] += hv * wh2;
    }
  }
  float bi0 = bi[lane], bi1 = bi[64 + lane], bi2 = bi[128 + lane];
  float bh0 = bh[lane], bh1 = bh[64 + lane], bh2 = bh[128 + lane];
#pragma unroll
  for (int i = 0; i < 4; ++i) {
    float r = sigmf(ir[i] + bi0 + hr[i] + bh0);
    float z = sigmf(iz[i] + bi1 + hz[i] + bh1);
    float nn = tanh_(ig[i] + bi2 + r * (hg[i] + bh2));
    float h = sh_out[n0 + i][lane];
    out[(size_t)(nb + n0 + i) * 64 + lane] = (1.f - z) * nn + z * h;
  }
}

// ============ all 3 Set2Set steps + head1; graph's node rows staged in LDS ============
__global__ __launch_bounds__(256) void k_s2s3(const float* __restrict__ out,
    const int* __restrict__ start, const float* __restrict__ Wli,
    const float* __restrict__ bli, const float* __restrict__ Wlh,
    const float* __restrict__ blh, const float* __restrict__ Wr1,
    const float* __restrict__ br1, float* __restrict__ y1) {
  __shared__ float sno[kNCap * 65];     // node rows, stride 65 (bank-conflict-free)
  __shared__ float ebuf[1024];
  __shared__ float qs[128], hls[64], cls[64], gates[256];
  __shared__ float part[4][64];
  __shared__ float sred[8];
  int b = blockIdx.x, t = threadIdx.x, lane = t & 63, w = t >> 6;
  int s0 = start[b], s1 = start[b + 1];
  int cnt = s1 - s0; if (cnt > 1024) cnt = 1024;
  int cstg = cnt < kNCap ? cnt : kNCap;
  // stage node rows (coalesced global read, one pass, reused across 3 iterations)
  for (int i = t; i < cstg * 64; i += 256)
    sno[(i >> 6) * 65 + (i & 63)] = out[(size_t)(s0 + (i >> 6)) * 64 + (i & 63)];
  if (t < 128) qs[t] = 0.f;
  if (t < 64) { hls[t] = 0.f; cls[t] = 0.f; }
  __syncthreads();
  for (int it = 0; it < 3; ++it) {
    // LSTM gates: all 256 threads, weights L2-hot, coalesced
    float g = bli[t] + blh[t];
    for (int j = 0; j < 128; ++j) g += qs[j] * Wli[j * 256 + t];
    for (int j = 0; j < 64; ++j) g += hls[j] * Wlh[j * 256 + t];
    gates[t] = g;
    __syncthreads();
    if (t < 64) {                      // gate order i, f, g, o
      float ig = sigmf(gates[t]), fg = sigmf(gates[64 + t]);
      float gg = tanh_(gates[128 + t]), og = sigmf(gates[192 + t]);
      float c = fg * cls[t] + ig * gg;
      float h = og * tanh_(c);
      cls[t] = c; hls[t] = h;
      qs[t] = h;                       // q part of q_star
    }
    __syncthreads();
    // e[n] = <out[n], q> : lane-per-node from LDS (bank-free via stride 65)
    for (int n = t; n < cnt; n += 256) {
      float e = 0.f;
      if (n < kNCap) {
        const float* row = &sno[n * 65];
#pragma unroll 16
        for (int d = 0; d < 64; ++d) e += row[d] * hls[d];
      } else {
        const float* row = out + (size_t)(s0 + n) * 64;
        for (int d = 0; d < 64; ++d) e += row[d] * hls[d];
      }
      ebuf[n] = e;
    }
    __syncthreads();
    float mx = -3.4e38f;
    for (int idx = t; idx < cnt; idx += 256) mx = fmaxf(mx, ebuf[idx]);
#pragma unroll
    for (int m = 1; m < 64; m <<= 1) mx = fmaxf(mx, __shfl_xor(mx, m, 64));
    if (lane == 0) sred[w] = mx;
    __syncthreads();
    mx = fmaxf(fmaxf(sred[0], sred[1]), fmaxf(sred[2], sred[3]));
    float s = 0.f;
    for (int idx = t; idx < cnt; idx += 256) {
      float a = __expf(ebuf[idx] - mx);
      ebuf[idx] = a; s += a;
    }
#pragma unroll
    for (int m = 1; m < 64; m <<= 1) s += __shfl_xor(s, m, 64);
    if (lane == 0) sred[4 + w] = s;
    __syncthreads();
    s = sred[4] + sred[5] + sred[6] + sred[7];
    float rs = 1.f / fmaxf(s, 1e-12f);
    // r_read[d] = sum_n a[n] * out[n][d] : waves split nodes, lane = d (LDS, bank-free)
    float pr = 0.f;
    for (int n = w; n < cnt; n += 4) {
      float a = ebuf[n];
      pr += a * ((n < kNCap) ? sno[n * 65 + lane] : out[(size_t)(s0 + n) * 64 + lane]);
    }
    part[w][lane] = pr;
    __syncthreads();
    if (t < 64)
      qs[64 + t] = (part[0][t] + part[1][t] + part[2][t] + part[3][t]) * rs;
    __syncthreads();
  }
  if (t < 64) {                        // head1: y1 = q_star @ Wr1 + br1
    float acc = br1[t];
    for (int j = 0; j < 128; ++j) acc += qs[j] * Wr1[j * 64 + t];
    y1[b * 64 + t] = acc;
  }
}

// ============ head2: BatchNorm (batch stats) + relu + Wr2 ============
__global__ __launch_bounds__(256) void k_head2(const float* __restrict__ y1,
    const float* __restrict__ gamma, const float* __restrict__ beta,
    const float* __restrict__ Wr2, const float* __restrict__ br2,
    float* __restrict__ outp) {
  __shared__ float mu[64], ri[64];
  int t = threadIdx.x;
  if (t < 64) {
    float s1 = 0.f, s2 = 0.f;
    for (int b = 0; b < kB; ++b) { float v = y1[b * 64 + t]; s1 += v; s2 += v * v; }
    float m = s1 / (float)kB;
    mu[t] = m; ri[t] = rsqrtf(s2 / (float)kB - m * m + 1e-5f);
  }
  __syncthreads();
  if (t < kB) {
    float acc = br2[0];
    for (int f = 0; f < 64; ++f) {
      float v = (y1[t * 64 + f] - mu[f]) * ri[f] * gamma[f] + beta[f];
      acc += fmaxf(v, 0.f) * Wr2[f];
    }
    outp[t] = acc;
  }
}

extern "C" void kernel_launch(void* const* d_in, const int* in_sizes, int n_in,
                              void* d_out, int out_size, void* d_ws, size_t ws_size,
                              hipStream_t stream) {
  const float* x     = (const float*)d_in[0];
  const int*   ei    = (const int*)d_in[1];
  const float* ea    = (const float*)d_in[2];
  const int*   batch = (const int*)d_in[3];
  const float* W0    = (const float*)d_in[4];
  const float* b0    = (const float*)d_in[5];
  const float* We1   = (const float*)d_in[6];
  const float* be1   = (const float*)d_in[7];
  const float* We2   = (const float*)d_in[8];
  const float* be2   = (const float*)d_in[9];
  const float* root  = (const float*)d_in[10];
  const float* convb = (const float*)d_in[11];
  const float* Wi    = (const float*)d_in[12];
  const float* bi    = (const float*)d_in[13];
  const float* Wh    = (const float*)d_in[14];
  const float* bh    = (const float*)d_in[15];
  const float* Wli   = (const float*)d_in[16];
  const float* bli   = (const float*)d_in[17];
  const float* Wlh   = (const float*)d_in[18];
  const float* blh   = (const float*)d_in[19];
  const float* Wr1   = (const float*)d_in[20];
  const float* br1   = (const float*)d_in[21];
  const float* gamma = (const float*)d_in[22];
  const float* beta  = (const float*)d_in[23];
  const float* Wr2   = (const float*)d_in[24];
  const float* br2   = (const float*)d_in[25];
  (void)in_sizes; (void)n_in; (void)out_size; (void)ws_size;

  char* ws = (char*)d_ws;
  size_t off = 0;
  auto take = [&](size_t bytes) {
    char* p = ws + off;
    off += (bytes + 255) & ~(size_t)255;
    return p;
  };
  // zero-region: deg + cnt (contiguous, one memset)
  float* deg  = (float*)take((size_t)kN * 4);
  int*   cnt  = (int*)take((size_t)kN * 4);
  size_t zeroBytes = off;
  int*   ptr   = (int*)take((size_t)(kN + 1) * 4);
  int*   csr   = (int*)take((size_t)kE * 4);
  int*   start = (int*)take(256 * 4);
  float* outn  = (float*)take((size_t)kN * kD * 4);
  float* msg0  = (float*)take((size_t)kEPad * kD * 4);                     // 6.4 MB
  float* msg1  = (float*)take((size_t)kEPad * kD * 4);                     // 6.4 MB
  unsigned short* hid7 = (unsigned short*)take((size_t)kGrp * 8192 * 2);   // 6.4 MB
  unsigned short* Bc2  = (unsigned short*)take((size_t)1032 * 512 * 2);    // 1.03 MB
  float* y1    = (float*)take((size_t)kB * 64 * 4);

  hipMemsetAsync(deg, 0, zeroBytes, stream);
  k_setup<<<kBlkSetup, 256, 0, stream>>>(x, W0, b0, ea, We1, be1, We2, be2, ei, batch,
                                         outn, hid7, Bc2, deg, start);
  k_csr<<<1, 256, 0, stream>>>(deg, ptr);
  k_scatter<<<(kE + 255) / 256, 256, 0, stream>>>(ei, ptr, cnt, csr);
  dim3 gm(kGrp, 2);
  for (int s = 0; s < 3; ++s) {
    k_msg7<<<gm, 256, 0, stream>>>(ei, outn, hid7, Bc2, msg0, msg1);
    k_update<<<kN / 16, 256, 0, stream>>>(msg0, msg1, ptr, csr, deg, root, convb,
                                          Wi, bi, Wh, bh, outn);
  }
  k_s2s3<<<kB, 256, 0, stream>>>(outn, start, Wli, bli, Wlh, blh, Wr1, br1, y1);
  k_head2<<<1, 256, 0, stream>>>(y1, gamma, beta, Wr2, br2, (float*)d_out);
}